// Round 6
// baseline (3432.293 us; speedup 1.0000x reference)
//
#include <hip/hip_runtime.h>

// MiniCPM-style decode step: L=8 B=4 H=16 HKV=8 D=64 S=2048 HID=1024 FF=2816
#define L_   8
#define B_   4
#define H_   16
#define HKV_ 8
#define D_   64
#define S_   2048
#define HID_ 1024
#define FF_  2816
#define EPS_ 1e-5f
#define MUP_ 0.49497474683058327f   // 1.4/sqrt(8)
#define SCALE_ 0.125f               // 1/sqrt(64)

// d_out is FLOAT32: [h 4096 | k_upd 16384 | v_upd 16384 | pos+1]
#define OUT_H   0
#define OUT_K   4096
#define OUT_V   (4096 + 16384)
#define OUT_POS (4096 + 16384 + 16384)

// ---------------- workspace layout (floats) ----------------
enum {
  WS_H    = 0,                       // 4096
  WS_H2   = 4096,                    // 4096
  WS_XN1  = 8192,                    // 4096
  WS_XN2  = 12288,                   // 4096
  WS_QP   = 16384,                   // 64*4*2048 = 524288
  WS_AM   = WS_QP + 524288,          // 1024
  WS_AL   = WS_AM + 1024,            // 1024
  WS_AO   = WS_AL + 1024,            // 65536
  WS_OP   = WS_AO + 65536,           // 524288
  WS_GP   = WS_OP + 524288,          // 360448
  WS_UP   = WS_GP + 360448,          // 360448
  WS_DP   = WS_UP + 360448,          // 180224
  WS_BAR  = WS_DP + 180224
};
// ---- barrier int layout (all one-shot per launch; zeroed by k_init) ----
// gbar idx = l*3+p, p<3, idx<24. 16 groups of 32 blocks.
#define GA(idx,g)  (((idx)*16 + (g))*16)            // [0, 6144)   arrival
#define RT(idx)    (6144 + (idx)*16)                // [6144,6528) root
#define GR(idx,g)  (6528 + ((idx)*16 + (g))*16)     // [6528,12672) release
#define FLG(f,g)   (12672 + ((f)*16 + (g))*16)      // [12672,16768) grouped flags f<16
#define SFL(s)     (16768 + (s)*16)                 // [16768,17024) single flags s<16
#define BAR_INTS   17408

__device__ __forceinline__ int read_pos_dev(const int* p) {
  int v = p[0];
  if (v >= 0 && v < S_) return v;
  float f = __int_as_float(v);
  if (f >= 0.0f && f <= (float)(S_ - 1)) return (int)(f + 0.5f);
  return 1500;
}

__device__ __forceinline__ float wave_sum(float v) {
  for (int m = 1; m < 64; m <<= 1) v += __shfl_xor(v, m);
  return v;
}
__device__ __forceinline__ float wave_max(float v) {
  for (int m = 1; m < 64; m <<= 1) v = fmaxf(v, __shfl_xor(v, m));
  return v;
}

#define SPIN_CAP (1 << 25)
__device__ __forceinline__ int bar_ld(int* p) {
  return __hip_atomic_load(p, __ATOMIC_RELAXED, __HIP_MEMORY_SCOPE_AGENT);
}

// ---- global barrier: hierarchical arrive + pushed release, low poll pressure ----
__device__ __forceinline__ void gbar(int* bar, int idx) {
  __syncthreads();
  if (threadIdx.x == 0) {
    __threadfence();
    int g = blockIdx.x >> 5;
    bool released = false;
    if (atomicAdd(bar + GA(idx, g), 1) == 31) {       // last of my 32-block group
      if (atomicAdd(bar + RT(idx), 1) == 15) {        // last group overall
        __threadfence();
        #pragma unroll
        for (int gg = 0; gg < 16; ++gg)
          __hip_atomic_store(bar + GR(idx, gg), 1, __ATOMIC_RELEASE,
                             __HIP_MEMORY_SCOPE_AGENT);
        released = true;
      }
    }
    if (!released) {
      int n = 0;
      while (bar_ld(bar + GR(idx, g)) == 0) {
        __builtin_amdgcn_s_sleep(16);
        if (++n > SPIN_CAP) break;
      }
    }
    __threadfence();
  }
  __syncthreads();
}

// grouped flag: 4 producers add to all 16 lines; pollers poll own group's line
__device__ __forceinline__ void gflag_add(int* bar, int f) {   // tid0, after sync
  __threadfence();
  #pragma unroll
  for (int g = 0; g < 16; ++g) atomicAdd(bar + FLG(f, g), 1);
}
__device__ __forceinline__ void gflag_wait(int* bar, int f) {
  if (threadIdx.x == 0) {
    int g = blockIdx.x >> 5, n = 0;
    while (bar_ld(bar + FLG(f, g)) < 4) {
      __builtin_amdgcn_s_sleep(16);
      if (++n > SPIN_CAP) break;
    }
    __threadfence();
  }
  __syncthreads();
}
// single-line flag: many producers, FEW pollers (<=4 blocks)
__device__ __forceinline__ void sflag_add(int* bar, int s) {   // tid0, after sync
  __threadfence();
  atomicAdd(bar + SFL(s), 1);
}
__device__ __forceinline__ void sflag_wait(int* bar, int s, int target) {
  if (threadIdx.x == 0) {
    int n = 0;
    while (bar_ld(bar + SFL(s)) < target) {
      __builtin_amdgcn_s_sleep(16);
      if (++n > SPIN_CAP) break;
    }
    __threadfence();
  }
  __syncthreads();
}

// ---------------- init: zero barrier region (every launch) ----------------
__global__ void k_init(float* ws) {
  int i = blockIdx.x * 256 + threadIdx.x;
  if (i < BAR_INTS) ((int*)(ws + WS_BAR))[i] = 0;
}

// ---------------- the mega-kernel ----------------
__global__ void __launch_bounds__(256, 2)
mega(const float* __restrict__ kcache, const float* __restrict__ vcache,
     const float* __restrict__ Wq, const float* __restrict__ Wk,
     const float* __restrict__ Wv, const float* __restrict__ Wo,
     const float* __restrict__ Wg, const float* __restrict__ Wu,
     const float* __restrict__ Wd, const float* __restrict__ n1,
     const float* __restrict__ n2, const float* __restrict__ fw,
     const float* __restrict__ x, const int* __restrict__ posp,
     float* ws, float* out) {
  const int bid = blockIdx.x, t = threadIdx.x;
  int* bar = (int*)(ws + WS_BAR);
  const int pos = read_pos_dev(posp);
  __shared__ __align__(16) float smem[1408];

  // QKV decomposition (used for prefetch + compute): 8 cb x 64 kcn of 16 rows
  const int qcb = bid & 7, qkcn = bid >> 3;
  const int qcol = qcb * 256 + t;
  float wqkv[16];
  {  // prefetch layer-0 qkv weights
    const float* W; int stride; int wcol;
    if (qcol < 1024)      { W = Wq; wcol = qcol;        stride = 1024; }
    else if (qcol < 1536) { W = Wk; wcol = qcol - 1024; stride = 512;  }
    else                  { W = Wv; wcol = qcol - 1536; stride = 512;  }
    const float* wp = W + (size_t)(qkcn * 16) * stride + wcol;
    #pragma unroll
    for (int i = 0; i < 16; ++i) wqkv[i] = wp[(size_t)i * stride];
  }

  // ---- pre-loop: h1 for layer 0 (blocks 0-3); pos scalar (block 4) ----
  if (bid < 4) {
    int b = bid;
    float hv[4]; float part = 0.f;
    for (int j = 0; j < 4; ++j) {
      int col = t + j * 256;
      float h = x[b * HID_ + col];
      hv[j] = h; part += h * h;
    }
    part = wave_sum(part);
    if ((t & 63) == 0) smem[t >> 6] = part;
    __syncthreads();
    float rs = rsqrtf((smem[0] + smem[1] + smem[2] + smem[3]) * (1.0f / HID_) + EPS_);
    for (int j = 0; j < 4; ++j) {
      int col = t + j * 256;
      ws[WS_H + b * HID_ + col] = hv[j];
      ws[WS_XN1 + b * HID_ + col] = hv[j] * rs * n1[col];
    }
    __syncthreads();
    if (t == 0) gflag_add(bar, 0);
  }
  if (bid == 4 && t == 0) out[OUT_POS] = (float)(pos + 1);

  #pragma unroll 1
  for (int l = 0; l < L_; ++l) {
    // ======== QKV: weights already in wqkv; wait xn1 flag, MAC, store QP ========
    gflag_wait(bar, l);
    {
      if (t < 64) smem[t] = ws[WS_XN1 + (t >> 4) * HID_ + qkcn * 16 + (t & 15)];
      __syncthreads();
      float a0 = 0.f, a1 = 0.f, a2 = 0.f, a3 = 0.f;
      #pragma unroll
      for (int i = 0; i < 16; ++i) {
        float w = wqkv[i];
        a0 += w * smem[i]; a1 += w * smem[16 + i];
        a2 += w * smem[32 + i]; a3 += w * smem[48 + i];
      }
      ws[WS_QP + ((size_t)qkcn * 4 + 0) * 2048 + qcol] = a0;
      ws[WS_QP + ((size_t)qkcn * 4 + 1) * 2048 + qcol] = a1;
      ws[WS_QP + ((size_t)qkcn * 4 + 2) * 2048 + qcol] = a2;
      ws[WS_QP + ((size_t)qkcn * 4 + 3) * 2048 + qcol] = a3;
    }
    gbar(bar, l * 3 + 0);

    // ======== ATTN: prefetch Wo; (b,kv) x 16 ns-chunks of 128 positions ========
    float wo8[8];
    {
      int ocb = bid & 3, okcn = bid >> 2;
      const float* owp = Wo + ((size_t)l * HID_ + okcn * 8) * HID_ + ocb * 256 + t;
      #pragma unroll
      for (int i = 0; i < 8; ++i) wo8[i] = owp[(size_t)i * HID_];
    }
    {
      int bh = bid >> 4, ns = bid & 15;
      int b = bh >> 3, kv = bh & 7;
      int w = t >> 6, lane = t & 63, r = lane >> 4, c = lane & 15;
      float* qL = smem;            // [2][64]
      float* knL = smem + 128;     // [64]
      float* vnL = smem + 192;     // [64]
      float* rawL = smem + 256;    // [256]
      float* sc0 = smem + 512;     // [128]
      float* sc1 = smem + 640;     // [128]
      float* red = smem + 768;     // [8]
      float* oacc = smem + 776;    // [2][4][64]
      int cg;
      if (t < 128)      cg = (kv * 2 + (t >> 6)) * 64 + (t & 63);
      else if (t < 192) cg = 1024 + kv * 64 + (t & 63);
      else              cg = 1536 + kv * 64 + (t & 63);
      float s = 0.f;
      #pragma unroll
      for (int q = 0; q < 64; ++q) s += ws[WS_QP + ((size_t)q * 4 + b) * 2048 + cg];
      rawL[t] = s;
      __syncthreads();
      {
        int dd = t & 63;
        if (t < 192) {
          int idx = dd & 31;
          float inv = expf(-(float)idx * (1.0f / 32.0f) * 9.210340371976184f);
          float ang = (float)pos * inv;
          float sn, cs; __sincosf(ang, &sn, &cs);
          float partner = rawL[t ^ 32];
          float rot = (dd < 32) ? -partner : partner;
          float v = rawL[t] * cs + rot * sn;
          if (t < 128) qL[(t >> 6) * 64 + dd] = v;
          else {
            knL[dd] = v;
            if (ns == 0) out[OUT_K + (((size_t)l * B_ + b) * HKV_ + kv) * 64 + dd] = v;
          }
        } else {
          vnL[dd] = rawL[t];
          if (ns == 0) out[OUT_V + (((size_t)l * B_ + b) * HKV_ + kv) * 64 + dd] = rawL[t];
        }
      }
      __syncthreads();
      const float* Kb = kcache + (((size_t)l * B_ + b) * HKV_ + kv) * S_ * 64;
      const float* Vb = vcache + (((size_t)l * B_ + b) * HKV_ + kv) * S_ * 64;
      int s0 = ns * 128;
      float4 q0 = *(float4*)&qL[4 * c];
      float4 q1 = *(float4*)&qL[64 + 4 * c];
      #pragma unroll
      for (int it = 0; it < 8; ++it) {
        int sp = s0 + it * 16 + w * 4 + r;
        float d0 = 0.f, d1 = 0.f;
        bool valid = (sp <= pos);
        if (valid) {
          float4 k4 = (sp == pos) ? *(float4*)&knL[4 * c]
                                  : *(const float4*)&Kb[(size_t)sp * 64 + 4 * c];
          d0 = k4.x * q0.x + k4.y * q0.y + k4.z * q0.z + k4.w * q0.w;
          d1 = k4.x * q1.x + k4.y * q1.y + k4.z * q1.z + k4.w * q1.w;
        }
        #pragma unroll
        for (int m = 1; m <= 8; m <<= 1) { d0 += __shfl_xor(d0, m); d1 += __shfl_xor(d1, m); }
        if (c == 0) {
          sc0[sp - s0] = valid ? d0 * SCALE_ : -1e30f;
          sc1[sp - s0] = valid ? d1 * SCALE_ : -1e30f;
        }
      }
      __syncthreads();
      float v0 = (t < 128) ? sc0[t] : -1e30f;
      float v1 = (t < 128) ? sc1[t] : -1e30f;
      float m0 = wave_max(v0), m1 = wave_max(v1);
      if (lane == 0) { red[w] = m0; red[4 + w] = m1; }
      __syncthreads();
      m0 = fmaxf(fmaxf(red[0], red[1]), fmaxf(red[2], red[3]));
      m1 = fmaxf(fmaxf(red[4], red[5]), fmaxf(red[6], red[7]));
      float e0 = (t < 128) ? expf(v0 - m0) : 0.f;
      float e1 = (t < 128) ? expf(v1 - m1) : 0.f;
      __syncthreads();
      if (t < 128) { sc0[t] = e0; sc1[t] = e1; }
      float se0 = wave_sum(e0), se1 = wave_sum(e1);
      if (lane == 0) { red[w] = se0; red[4 + w] = se1; }
      __syncthreads();
      if (t == 0) {
        int base = ((b * HKV_ + kv) * 2) * 16 + ns;
        ws[WS_AM + base] = m0;       ws[WS_AM + base + 16] = m1;
        ws[WS_AL + base] = red[0] + red[1] + red[2] + red[3];
        ws[WS_AL + base + 16] = red[4] + red[5] + red[6] + red[7];
      }
      float4 a0 = make_float4(0.f, 0.f, 0.f, 0.f);
      float4 a1 = make_float4(0.f, 0.f, 0.f, 0.f);
      #pragma unroll
      for (int it = 0; it < 8; ++it) {
        int sp = s0 + it * 16 + w * 4 + r;
        if (sp <= pos) {
          float4 v4 = (sp == pos) ? *(float4*)&vnL[4 * c]
                                  : *(const float4*)&Vb[(size_t)sp * 64 + 4 * c];
          float p0 = sc0[sp - s0], p1 = sc1[sp - s0];
          a0.x += p0 * v4.x; a0.y += p0 * v4.y; a0.z += p0 * v4.z; a0.w += p0 * v4.w;
          a1.x += p1 * v4.x; a1.y += p1 * v4.y; a1.z += p1 * v4.z; a1.w += p1 * v4.w;
        }
      }
      #pragma unroll
      for (int m = 16; m <= 32; m <<= 1) {
        a0.x += __shfl_xor(a0.x, m); a0.y += __shfl_xor(a0.y, m);
        a0.z += __shfl_xor(a0.z, m); a0.w += __shfl_xor(a0.w, m);
        a1.x += __shfl_xor(a1.x, m); a1.y += __shfl_xor(a1.y, m);
        a1.z += __shfl_xor(a1.z, m); a1.w += __shfl_xor(a1.w, m);
      }
      if (r == 0) {
        *(float4*)&oacc[w * 64 + 4 * c] = a0;
        *(float4*)&oacc[256 + w * 64 + 4 * c] = a1;
      }
      __syncthreads();
      if (t < 64) {
        float r0 = oacc[t] + oacc[64 + t] + oacc[128 + t] + oacc[192 + t];
        float r1 = oacc[256 + t] + oacc[320 + t] + oacc[384 + t] + oacc[448 + t];
        int h0 = kv * 2;
        ws[WS_AO + (((size_t)(b * H_ + h0)) * 16 + ns) * 64 + t] = r0;
        ws[WS_AO + (((size_t)(b * H_ + h0 + 1)) * 16 + ns) * 64 + t] = r1;
      }
    }
    gbar(bar, l * 3 + 1);

    // ======== OPROJ (all 512): softmax-combine + MAC with prefetched wo8 ========
    {
      int cb = bid & 3, kcn = bid >> 2;
      int col = cb * 256 + t;
      if (t < 32) {
        int jj = t >> 2, bb = t & 3;
        int dim = kcn * 8 + jj, h = dim >> 6, d = dim & 63;
        int mb = ((bb * HKV_ + (h >> 1)) * 2 + (h & 1)) * 16;
        float mx = -1e30f;
        #pragma unroll
        for (int n = 0; n < 16; ++n) mx = fmaxf(mx, ws[WS_AM + mb + n]);
        float ls = 0.f, os = 0.f;
        #pragma unroll
        for (int n = 0; n < 16; ++n) {
          float wg = expf(ws[WS_AM + mb + n] - mx);
          ls += wg * ws[WS_AL + mb + n];
          os += wg * ws[WS_AO + (((size_t)(bb * H_ + h)) * 16 + n) * 64 + d];
        }
        smem[jj * 4 + bb] = os / ls;
      }
      __syncthreads();
      float a0 = 0.f, a1 = 0.f, a2 = 0.f, a3 = 0.f;
      #pragma unroll
      for (int i = 0; i < 8; ++i) {
        float w = wo8[i];
        a0 += w * smem[i * 4 + 0]; a1 += w * smem[i * 4 + 1];
        a2 += w * smem[i * 4 + 2]; a3 += w * smem[i * 4 + 3];
      }
      ws[WS_OP + ((size_t)kcn * 4 + 0) * 1024 + col] = a0;
      ws[WS_OP + ((size_t)kcn * 4 + 1) * 1024 + col] = a1;
      ws[WS_OP + ((size_t)kcn * 4 + 2) * 1024 + col] = a2;
      ws[WS_OP + ((size_t)kcn * 4 + 3) * 1024 + col] = a3;
      __syncthreads();
      if (t == 0) sflag_add(bar, l);        // OPF: 512 producers, 4 pollers
    }

    // ======== XN2 (blocks 0-3 wait OPF) + GATE/UP (blocks 0-351) ========
    if (bid < 4) {
      sflag_wait(bar, l, 512);
      int b = bid;
      float hv[4]; float part = 0.f;
      for (int j = 0; j < 4; ++j) {
        int col = t + j * 256;
        float s = 0.f;
        #pragma unroll
        for (int k2 = 0; k2 < 128; ++k2) s += ws[WS_OP + ((size_t)k2 * 4 + b) * 1024 + col];
        float h = ws[WS_H + b * HID_ + col] + MUP_ * s;
        hv[j] = h; part += h * h;
      }
      part = wave_sum(part);
      if ((t & 63) == 0) smem[t >> 6] = part;
      __syncthreads();
      float rs = rsqrtf((smem[0] + smem[1] + smem[2] + smem[3]) * (1.0f / HID_) + EPS_);
      for (int j = 0; j < 4; ++j) {
        int col = t + j * 256;
        ws[WS_H2 + b * HID_ + col] = hv[j];
        ws[WS_XN2 + b * HID_ + col] = hv[j] * rs * n2[l * HID_ + col];
      }
      __syncthreads();
      if (t == 0) gflag_add(bar, 8 + l);
    }
    if (bid < 352) {
      int cb = bid % 11, kcn = bid / 11;
      int col = cb * 256 + t;
      const float* wg = Wg + ((size_t)l * HID_ + kcn * 32) * FF_ + col;
      const float* wu = Wu + ((size_t)l * HID_ + kcn * 32) * FF_ + col;
      float gv[32], uv[32];
      #pragma unroll
      for (int i = 0; i < 32; ++i) { gv[i] = wg[(size_t)i * FF_]; uv[i] = wu[(size_t)i * FF_]; }
      gflag_wait(bar, 8 + l);
      if (t < 128) smem[t] = ws[WS_XN2 + (t >> 5) * HID_ + kcn * 32 + (t & 31)];
      __syncthreads();
      float g0 = 0.f, g1 = 0.f, g2 = 0.f, g3 = 0.f;
      float u0 = 0.f, u1 = 0.f, u2 = 0.f, u3 = 0.f;
      #pragma unroll
      for (int i = 0; i < 32; ++i) {
        float g = gv[i], u = uv[i];
        float x0 = smem[i], x1 = smem[32 + i], x2 = smem[64 + i], x3 = smem[96 + i];
        g0 += g * x0; g1 += g * x1; g2 += g * x2; g3 += g * x3;
        u0 += u * x0; u1 += u * x1; u2 += u * x2; u3 += u * x3;
      }
      *(float4*)(ws + WS_GP + ((size_t)kcn * FF_ + col) * 4) = make_float4(g0, g1, g2, g3);
      *(float4*)(ws + WS_UP + ((size_t)kcn * FF_ + col) * 4) = make_float4(u0, u1, u2, u3);
      __syncthreads();
    }
    gbar(bar, l * 3 + 2);

    // ======== DOWN (blocks 0-175) + prefetch next-layer QKV weights (all) ========
    if (bid < 176) {
      int cb = bid & 3, kcn = bid >> 2;
      int col = cb * 256 + t;
      const float* wp = Wd + ((size_t)l * FF_ + kcn * 64) * HID_ + col;
      float wv[64];
      #pragma unroll
      for (int i = 0; i < 64; ++i) wv[i] = wp[(size_t)i * HID_];
      {
        int jj = t >> 2, bb = t & 3;
        int f = kcn * 64 + jj;
        float g = 0.f, u = 0.f;
        #pragma unroll
        for (int k2 = 0; k2 < 32; ++k2) {
          g += ws[WS_GP + ((size_t)k2 * FF_ + f) * 4 + bb];
          u += ws[WS_UP + ((size_t)k2 * FF_ + f) * 4 + bb];
        }
        float sig = 1.f / (1.f + expf(-g));
        smem[jj * 4 + bb] = g * sig * u;
      }
      __syncthreads();
      float a0 = 0.f, a1 = 0.f, a2 = 0.f, a3 = 0.f;
      #pragma unroll
      for (int i = 0; i < 64; ++i) {
        float w = wv[i];
        a0 += w * smem[i * 4 + 0]; a1 += w * smem[i * 4 + 1];
        a2 += w * smem[i * 4 + 2]; a3 += w * smem[i * 4 + 3];
      }
      ws[WS_DP + ((size_t)kcn * 4 + 0) * 1024 + col] = a0;
      ws[WS_DP + ((size_t)kcn * 4 + 1) * 1024 + col] = a1;
      ws[WS_DP + ((size_t)kcn * 4 + 2) * 1024 + col] = a2;
      ws[WS_DP + ((size_t)kcn * 4 + 3) * 1024 + col] = a3;
      __syncthreads();
      if (t == 0) sflag_add(bar, 8 + l);     // DPF: 176 producers, 4 pollers
    }
    {  // prefetch QKV weights for l+1 (weights are read-only: safe over sync)
      int lq = (l + 1 < L_) ? l + 1 : l;
      const float* W; int stride; int wcol;
      if (qcol < 1024)      { W = Wq + (size_t)lq * HID_ * 1024; wcol = qcol;        stride = 1024; }
      else if (qcol < 1536) { W = Wk + (size_t)lq * HID_ * 512;  wcol = qcol - 1024; stride = 512;  }
      else                  { W = Wv + (size_t)lq * HID_ * 512;  wcol = qcol - 1536; stride = 512;  }
      const float* wp = W + (size_t)(qkcn * 16) * stride + wcol;
      #pragma unroll
      for (int i = 0; i < 16; ++i) wqkv[i] = wp[(size_t)i * stride];
    }

    // ======== H1 (blocks 0-3): wait DPF, residual + rms -> XN1(l+1)/out ========
    if (bid < 4) {
      sflag_wait(bar, 8 + l, 176);
      int b = bid;
      float hv[4]; float part = 0.f;
      for (int j = 0; j < 4; ++j) {
        int col = t + j * 256;
        float s = 0.f;
        #pragma unroll
        for (int k2 = 0; k2 < 44; ++k2) s += ws[WS_DP + ((size_t)k2 * 4 + b) * 1024 + col];
        float h = ws[WS_H2 + b * HID_ + col] + MUP_ * s;
        hv[j] = h; part += h * h;
      }
      part = wave_sum(part);
      if ((t & 63) == 0) smem[t >> 6] = part;
      __syncthreads();
      float rs = rsqrtf((smem[0] + smem[1] + smem[2] + smem[3]) * (1.0f / HID_) + EPS_);
      if (l == L_ - 1) {
        for (int j = 0; j < 4; ++j) {
          int col = t + j * 256;
          out[OUT_H + b * HID_ + col] = hv[j] * rs * fw[col];
        }
      } else {
        for (int j = 0; j < 4; ++j) {
          int col = t + j * 256;
          ws[WS_H + b * HID_ + col] = hv[j];
          ws[WS_XN1 + b * HID_ + col] = hv[j] * rs * n1[(l + 1) * HID_ + col];
        }
        __syncthreads();
        if (t == 0) gflag_add(bar, l + 1);
      }
    }
  }
}

extern "C" void kernel_launch(void* const* d_in, const int* in_sizes, int n_in,
                              void* d_out, int out_size, void* d_ws, size_t ws_size,
                              hipStream_t stream) {
  const float* x   = (const float*)d_in[0];
  const float* kcp = (const float*)d_in[1];
  const float* vcp = (const float*)d_in[2];
  const float* Wq  = (const float*)d_in[3];
  const float* Wk  = (const float*)d_in[4];
  const float* Wv  = (const float*)d_in[5];
  const float* Wo  = (const float*)d_in[6];
  const float* Wg  = (const float*)d_in[7];
  const float* Wu  = (const float*)d_in[8];
  const float* Wd  = (const float*)d_in[9];
  const float* n1  = (const float*)d_in[10];
  const float* n2  = (const float*)d_in[11];
  const float* fw  = (const float*)d_in[12];
  const int*   pos = (const int*)d_in[13];
  float* ws  = (float*)d_ws;
  float* out = (float*)d_out;

  k_init<<<(BAR_INTS + 255) / 256, 256, 0, stream>>>(ws);

  void* args[] = { (void*)&kcp, (void*)&vcp, (void*)&Wq, (void*)&Wk, (void*)&Wv,
                   (void*)&Wo, (void*)&Wg, (void*)&Wu, (void*)&Wd, (void*)&n1,
                   (void*)&n2, (void*)&fw, (void*)&x, (void*)&pos,
                   (void*)&ws, (void*)&out };
  hipError_t e = hipLaunchCooperativeKernel((const void*)mega, dim3(512), dim3(256),
                                            args, 0, stream);
  if (e != hipSuccess) {
    mega<<<512, 256, 0, stream>>>(kcp, vcp, Wq, Wk, Wv, Wo, Wg, Wu, Wd,
                                  n1, n2, fw, x, pos, ws, out);
  }
}

// Round 7
// 2337.031 us; speedup vs baseline: 1.4687x; 1.4687x over previous
//
#include <hip/hip_runtime.h>

// MiniCPM-style decode step: L=8 B=4 H=16 HKV=8 D=64 S=2048 HID=1024 FF=2816
#define L_   8
#define B_   4
#define H_   16
#define HKV_ 8
#define D_   64
#define S_   2048
#define HID_ 1024
#define FF_  2816
#define EPS_ 1e-5f
#define MUP_ 0.49497474683058327f   // 1.4/sqrt(8)
#define SCALE_ 0.125f               // 1/sqrt(64)

// d_out is FLOAT32: [h 4096 | k_upd 16384 | v_upd 16384 | pos+1]
#define OUT_H   0
#define OUT_K   4096
#define OUT_V   (4096 + 16384)
#define OUT_POS (4096 + 16384 + 16384)

// ---------------- workspace layout (floats) ----------------
enum {
  WS_H    = 0,                       // 4096
  WS_H2   = 4096,                    // 4096
  WS_XN1  = 8192,                    // 4096
  WS_XN2  = 12288,                   // 4096
  WS_QP   = 16384,                   // 64*4*2048 = 524288
  WS_AM   = WS_QP + 524288,          // 1024
  WS_AL   = WS_AM + 1024,            // 1024
  WS_AO   = WS_AL + 1024,            // 65536
  WS_OP   = WS_AO + 65536,           // 524288
  WS_GP   = WS_OP + 524288,          // 360448
  WS_UP   = WS_GP + 360448,          // 360448
  WS_DP   = WS_UP + 360448,          // 180224
  WS_BAR  = WS_DP + 180224
};
// ---- barrier int layout (one-shot per launch; zeroed by k_init) ----
#define GA(idx,g)  (((idx)*16 + (g))*16)            // arrival groups
#define RT(idx)    (6144 + (idx)*16)                // root
#define GR(idx,g)  (6528 + ((idx)*16 + (g))*16)     // release per group
#define FLG(f,g)   (12672 + ((f)*16 + (g))*16)      // grouped flags f<16
#define SFL(s)     (16768 + (s)*16)                 // single flags s<16
#define BAR_INTS   17408

__device__ __forceinline__ int read_pos_dev(const int* p) {
  int v = p[0];
  if (v >= 0 && v < S_) return v;
  float f = __int_as_float(v);
  if (f >= 0.0f && f <= (float)(S_ - 1)) return (int)(f + 0.5f);
  return 1500;
}

__device__ __forceinline__ float wave_sum(float v) {
  for (int m = 1; m < 64; m <<= 1) v += __shfl_xor(v, m);
  return v;
}
__device__ __forceinline__ float wave_max(float v) {
  for (int m = 1; m < 64; m <<= 1) v = fmaxf(v, __shfl_xor(v, m));
  return v;
}

// ---- memory-side (agent-coherent, fence-free) scalar access ----
__device__ __forceinline__ float ldg_a(const float* p) {
  return __hip_atomic_load(p, __ATOMIC_RELAXED, __HIP_MEMORY_SCOPE_AGENT);
}
__device__ __forceinline__ void stg_a(float* p, float v) {
  __hip_atomic_store(p, v, __ATOMIC_RELAXED, __HIP_MEMORY_SCOPE_AGENT);
}

#define SPIN_CAP (1 << 25)
__device__ __forceinline__ int bar_ld(int* p) {
  return __hip_atomic_load(p, __ATOMIC_RELAXED, __HIP_MEMORY_SCOPE_AGENT);
}

// ---- global barrier: hierarchical, NO fences (data goes memory-side) ----
__device__ __forceinline__ void gbar(int* bar, int idx) {
  __syncthreads();                    // drains each wave's vmcnt (stores done)
  if (threadIdx.x == 0) {
    int g = blockIdx.x >> 5;
    bool released = false;
    if (atomicAdd(bar + GA(idx, g), 1) == 31) {
      if (atomicAdd(bar + RT(idx), 1) == 15) {
        #pragma unroll
        for (int gg = 0; gg < 16; ++gg)
          __hip_atomic_store(bar + GR(idx, gg), 1, __ATOMIC_RELAXED,
                             __HIP_MEMORY_SCOPE_AGENT);
        released = true;
      }
    }
    if (!released) {
      int n = 0;
      while (bar_ld(bar + GR(idx, g)) == 0) {
        __builtin_amdgcn_s_sleep(8);
        if (++n > SPIN_CAP) break;
      }
    }
  }
  __syncthreads();
}

__device__ __forceinline__ void gflag_add(int* bar, int f) {   // tid0, after sync
  #pragma unroll
  for (int g = 0; g < 16; ++g) atomicAdd(bar + FLG(f, g), 1);
}
__device__ __forceinline__ void gflag_wait(int* bar, int f) {
  if (threadIdx.x == 0) {
    int g = blockIdx.x >> 5, n = 0;
    while (bar_ld(bar + FLG(f, g)) < 4) {
      __builtin_amdgcn_s_sleep(8);
      if (++n > SPIN_CAP) break;
    }
  }
  __syncthreads();
}
__device__ __forceinline__ void sflag_add(int* bar, int s) {
  atomicAdd(bar + SFL(s), 1);
}
__device__ __forceinline__ void sflag_wait(int* bar, int s, int target) {
  if (threadIdx.x == 0) {
    int n = 0;
    while (bar_ld(bar + SFL(s)) < target) {
      __builtin_amdgcn_s_sleep(8);
      if (++n > SPIN_CAP) break;
    }
  }
  __syncthreads();
}

// ---------------- init: zero barrier region (every launch) ----------------
__global__ void k_init(float* ws) {
  int i = blockIdx.x * 256 + threadIdx.x;
  if (i < BAR_INTS) ((int*)(ws + WS_BAR))[i] = 0;
}

// ---------------- the mega-kernel ----------------
__global__ void __launch_bounds__(256, 2)
mega(const float* __restrict__ kcache, const float* __restrict__ vcache,
     const float* __restrict__ Wq, const float* __restrict__ Wk,
     const float* __restrict__ Wv, const float* __restrict__ Wo,
     const float* __restrict__ Wg, const float* __restrict__ Wu,
     const float* __restrict__ Wd, const float* __restrict__ n1,
     const float* __restrict__ n2, const float* __restrict__ fw,
     const float* __restrict__ x, const int* __restrict__ posp,
     float* ws, float* out) {
  const int bid = blockIdx.x, t = threadIdx.x;
  int* bar = (int*)(ws + WS_BAR);
  const int pos = read_pos_dev(posp);
  __shared__ __align__(16) float smem[1408];

  // QKV decomposition: 8 cb x 64 kcn of 16 rows
  const int qcb = bid & 7, qkcn = bid >> 3;
  const int qcol = qcb * 256 + t;
  float wqkv[16];
  {  // prefetch layer-0 qkv weights (plain cached loads; read-only)
    const float* W; int stride; int wcol;
    if (qcol < 1024)      { W = Wq; wcol = qcol;        stride = 1024; }
    else if (qcol < 1536) { W = Wk; wcol = qcol - 1024; stride = 512;  }
    else                  { W = Wv; wcol = qcol - 1536; stride = 512;  }
    const float* wp = W + (size_t)(qkcn * 16) * stride + wcol;
    #pragma unroll
    for (int i = 0; i < 16; ++i) wqkv[i] = wp[(size_t)i * stride];
  }

  // ---- pre-loop: h1 for layer 0 (blocks 0-3); pos scalar (block 4) ----
  if (bid < 4) {
    int b = bid;
    float hv[4]; float part = 0.f;
    for (int j = 0; j < 4; ++j) {
      int col = t + j * 256;
      float h = x[b * HID_ + col];
      hv[j] = h; part += h * h;
    }
    part = wave_sum(part);
    if ((t & 63) == 0) smem[t >> 6] = part;
    __syncthreads();
    float rs = rsqrtf((smem[0] + smem[1] + smem[2] + smem[3]) * (1.0f / HID_) + EPS_);
    for (int j = 0; j < 4; ++j) {
      int col = t + j * 256;
      ws[WS_H + b * HID_ + col] = hv[j];                       // block-private
      stg_a(ws + WS_XN1 + b * HID_ + col, hv[j] * rs * n1[col]); // shared
    }
    __syncthreads();
    if (t == 0) gflag_add(bar, 0);
  }
  if (bid == 4 && t == 0) out[OUT_POS] = (float)(pos + 1);

  #pragma unroll 1
  for (int l = 0; l < L_; ++l) {
    // ======== QKV: weights in wqkv; wait xn1 flag, MAC, store QP ========
    gflag_wait(bar, l);
    {
      if (t < 64) smem[t] = ldg_a(ws + WS_XN1 + (t >> 4) * HID_ + qkcn * 16 + (t & 15));
      __syncthreads();
      float a0 = 0.f, a1 = 0.f, a2 = 0.f, a3 = 0.f;
      #pragma unroll
      for (int i = 0; i < 16; ++i) {
        float w = wqkv[i];
        a0 += w * smem[i]; a1 += w * smem[16 + i];
        a2 += w * smem[32 + i]; a3 += w * smem[48 + i];
      }
      stg_a(ws + WS_QP + ((size_t)qkcn * 4 + 0) * 2048 + qcol, a0);
      stg_a(ws + WS_QP + ((size_t)qkcn * 4 + 1) * 2048 + qcol, a1);
      stg_a(ws + WS_QP + ((size_t)qkcn * 4 + 2) * 2048 + qcol, a2);
      stg_a(ws + WS_QP + ((size_t)qkcn * 4 + 3) * 2048 + qcol, a3);
    }
    gbar(bar, l * 3 + 0);

    // ======== ATTN: prefetch Wo; (b,kv) x 16 ns-chunks of 128 positions ========
    float wo8[8];
    {
      int ocb = bid & 3, okcn = bid >> 2;
      const float* owp = Wo + ((size_t)l * HID_ + okcn * 8) * HID_ + ocb * 256 + t;
      #pragma unroll
      for (int i = 0; i < 8; ++i) wo8[i] = owp[(size_t)i * HID_];
    }
    {
      int bh = bid >> 4, ns = bid & 15;
      int b = bh >> 3, kv = bh & 7;
      int w = t >> 6, lane = t & 63, r = lane >> 4, c = lane & 15;
      float* qL = smem;            // [2][64]
      float* knL = smem + 128;     // [64]
      float* vnL = smem + 192;     // [64]
      float* rawL = smem + 256;    // [256]
      float* sc0 = smem + 512;     // [128]
      float* sc1 = smem + 640;     // [128]
      float* red = smem + 768;     // [8]
      float* oacc = smem + 776;    // [2][4][64]
      int cg;
      if (t < 128)      cg = (kv * 2 + (t >> 6)) * 64 + (t & 63);
      else if (t < 192) cg = 1024 + kv * 64 + (t & 63);
      else              cg = 1536 + kv * 64 + (t & 63);
      float s = 0.f;
      #pragma unroll
      for (int q = 0; q < 64; ++q) s += ldg_a(ws + WS_QP + ((size_t)q * 4 + b) * 2048 + cg);
      rawL[t] = s;
      __syncthreads();
      {
        int dd = t & 63;
        if (t < 192) {
          int idx = dd & 31;
          float inv = expf(-(float)idx * (1.0f / 32.0f) * 9.210340371976184f);
          float ang = (float)pos * inv;
          float sn, cs; __sincosf(ang, &sn, &cs);
          float partner = rawL[t ^ 32];
          float rot = (dd < 32) ? -partner : partner;
          float v = rawL[t] * cs + rot * sn;
          if (t < 128) qL[(t >> 6) * 64 + dd] = v;
          else {
            knL[dd] = v;
            if (ns == 0) out[OUT_K + (((size_t)l * B_ + b) * HKV_ + kv) * 64 + dd] = v;
          }
        } else {
          vnL[dd] = rawL[t];
          if (ns == 0) out[OUT_V + (((size_t)l * B_ + b) * HKV_ + kv) * 64 + dd] = rawL[t];
        }
      }
      __syncthreads();
      const float* Kb = kcache + (((size_t)l * B_ + b) * HKV_ + kv) * S_ * 64;
      const float* Vb = vcache + (((size_t)l * B_ + b) * HKV_ + kv) * S_ * 64;
      int s0 = ns * 128;
      float4 q0 = *(float4*)&qL[4 * c];
      float4 q1 = *(float4*)&qL[64 + 4 * c];
      #pragma unroll
      for (int it = 0; it < 8; ++it) {
        int sp = s0 + it * 16 + w * 4 + r;
        float d0 = 0.f, d1 = 0.f;
        bool valid = (sp <= pos);
        if (valid) {
          float4 k4 = (sp == pos) ? *(float4*)&knL[4 * c]
                                  : *(const float4*)&Kb[(size_t)sp * 64 + 4 * c];
          d0 = k4.x * q0.x + k4.y * q0.y + k4.z * q0.z + k4.w * q0.w;
          d1 = k4.x * q1.x + k4.y * q1.y + k4.z * q1.z + k4.w * q1.w;
        }
        #pragma unroll
        for (int m = 1; m <= 8; m <<= 1) { d0 += __shfl_xor(d0, m); d1 += __shfl_xor(d1, m); }
        if (c == 0) {
          sc0[sp - s0] = valid ? d0 * SCALE_ : -1e30f;
          sc1[sp - s0] = valid ? d1 * SCALE_ : -1e30f;
        }
      }
      __syncthreads();
      float v0 = (t < 128) ? sc0[t] : -1e30f;
      float v1 = (t < 128) ? sc1[t] : -1e30f;
      float m0 = wave_max(v0), m1 = wave_max(v1);
      if (lane == 0) { red[w] = m0; red[4 + w] = m1; }
      __syncthreads();
      m0 = fmaxf(fmaxf(red[0], red[1]), fmaxf(red[2], red[3]));
      m1 = fmaxf(fmaxf(red[4], red[5]), fmaxf(red[6], red[7]));
      float e0 = (t < 128) ? expf(v0 - m0) : 0.f;
      float e1 = (t < 128) ? expf(v1 - m1) : 0.f;
      __syncthreads();
      if (t < 128) { sc0[t] = e0; sc1[t] = e1; }
      float se0 = wave_sum(e0), se1 = wave_sum(e1);
      if (lane == 0) { red[w] = se0; red[4 + w] = se1; }
      __syncthreads();
      if (t == 0) {
        int base = ((b * HKV_ + kv) * 2) * 16 + ns;
        stg_a(ws + WS_AM + base, m0);       stg_a(ws + WS_AM + base + 16, m1);
        stg_a(ws + WS_AL + base, red[0] + red[1] + red[2] + red[3]);
        stg_a(ws + WS_AL + base + 16, red[4] + red[5] + red[6] + red[7]);
      }
      float4 a0 = make_float4(0.f, 0.f, 0.f, 0.f);
      float4 a1 = make_float4(0.f, 0.f, 0.f, 0.f);
      #pragma unroll
      for (int it = 0; it < 8; ++it) {
        int sp = s0 + it * 16 + w * 4 + r;
        if (sp <= pos) {
          float4 v4 = (sp == pos) ? *(float4*)&vnL[4 * c]
                                  : *(const float4*)&Vb[(size_t)sp * 64 + 4 * c];
          float p0 = sc0[sp - s0], p1 = sc1[sp - s0];
          a0.x += p0 * v4.x; a0.y += p0 * v4.y; a0.z += p0 * v4.z; a0.w += p0 * v4.w;
          a1.x += p1 * v4.x; a1.y += p1 * v4.y; a1.z += p1 * v4.z; a1.w += p1 * v4.w;
        }
      }
      #pragma unroll
      for (int m = 16; m <= 32; m <<= 1) {
        a0.x += __shfl_xor(a0.x, m); a0.y += __shfl_xor(a0.y, m);
        a0.z += __shfl_xor(a0.z, m); a0.w += __shfl_xor(a0.w, m);
        a1.x += __shfl_xor(a1.x, m); a1.y += __shfl_xor(a1.y, m);
        a1.z += __shfl_xor(a1.z, m); a1.w += __shfl_xor(a1.w, m);
      }
      if (r == 0) {
        *(float4*)&oacc[w * 64 + 4 * c] = a0;
        *(float4*)&oacc[256 + w * 64 + 4 * c] = a1;
      }
      __syncthreads();
      if (t < 64) {
        float r0 = oacc[t] + oacc[64 + t] + oacc[128 + t] + oacc[192 + t];
        float r1 = oacc[256 + t] + oacc[320 + t] + oacc[384 + t] + oacc[448 + t];
        int h0 = kv * 2;
        stg_a(ws + WS_AO + (((size_t)(b * H_ + h0)) * 16 + ns) * 64 + t, r0);
        stg_a(ws + WS_AO + (((size_t)(b * H_ + h0 + 1)) * 16 + ns) * 64 + t, r1);
      }
    }
    gbar(bar, l * 3 + 1);

    // ======== OPROJ (all 512): softmax-combine + MAC with prefetched wo8 ========
    {
      int cb = bid & 3, kcn = bid >> 2;
      int col = cb * 256 + t;
      if (t < 32) {
        int jj = t >> 2, bb = t & 3;
        int dim = kcn * 8 + jj, h = dim >> 6, d = dim & 63;
        int mb = ((bb * HKV_ + (h >> 1)) * 2 + (h & 1)) * 16;
        float mx = -1e30f;
        #pragma unroll
        for (int n = 0; n < 16; ++n) mx = fmaxf(mx, ldg_a(ws + WS_AM + mb + n));
        float ls = 0.f, os = 0.f;
        #pragma unroll
        for (int n = 0; n < 16; ++n) {
          float wg = expf(ldg_a(ws + WS_AM + mb + n) - mx);
          ls += wg * ldg_a(ws + WS_AL + mb + n);
          os += wg * ldg_a(ws + WS_AO + (((size_t)(bb * H_ + h)) * 16 + n) * 64 + d);
        }
        smem[jj * 4 + bb] = os / ls;
      }
      __syncthreads();
      float a0 = 0.f, a1 = 0.f, a2 = 0.f, a3 = 0.f;
      #pragma unroll
      for (int i = 0; i < 8; ++i) {
        float w = wo8[i];
        a0 += w * smem[i * 4 + 0]; a1 += w * smem[i * 4 + 1];
        a2 += w * smem[i * 4 + 2]; a3 += w * smem[i * 4 + 3];
      }
      stg_a(ws + WS_OP + ((size_t)kcn * 4 + 0) * 1024 + col, a0);
      stg_a(ws + WS_OP + ((size_t)kcn * 4 + 1) * 1024 + col, a1);
      stg_a(ws + WS_OP + ((size_t)kcn * 4 + 2) * 1024 + col, a2);
      stg_a(ws + WS_OP + ((size_t)kcn * 4 + 3) * 1024 + col, a3);
      __syncthreads();
      if (t == 0) sflag_add(bar, l);        // OPF: 512 producers, 4 pollers
    }

    // ======== XN2 (blocks 0-3 wait OPF) + GATE/UP (blocks 0-351) ========
    if (bid < 4) {
      sflag_wait(bar, l, 512);
      int b = bid;
      float hv[4]; float part = 0.f;
      for (int j = 0; j < 4; ++j) {
        int col = t + j * 256;
        float s = 0.f;
        #pragma unroll
        for (int k2 = 0; k2 < 128; ++k2) s += ldg_a(ws + WS_OP + ((size_t)k2 * 4 + b) * 1024 + col);
        float h = ws[WS_H + b * HID_ + col] + MUP_ * s;
        hv[j] = h; part += h * h;
      }
      part = wave_sum(part);
      if ((t & 63) == 0) smem[t >> 6] = part;
      __syncthreads();
      float rs = rsqrtf((smem[0] + smem[1] + smem[2] + smem[3]) * (1.0f / HID_) + EPS_);
      for (int j = 0; j < 4; ++j) {
        int col = t + j * 256;
        ws[WS_H2 + b * HID_ + col] = hv[j];                        // block-private
        stg_a(ws + WS_XN2 + b * HID_ + col, hv[j] * rs * n2[l * HID_ + col]);
      }
      __syncthreads();
      if (t == 0) gflag_add(bar, 8 + l);
    }
    if (bid < 352) {
      int cb = bid % 11, kcn = bid / 11;
      int col = cb * 256 + t;
      const float* wg = Wg + ((size_t)l * HID_ + kcn * 32) * FF_ + col;
      const float* wu = Wu + ((size_t)l * HID_ + kcn * 32) * FF_ + col;
      float gv[32], uv[32];
      #pragma unroll
      for (int i = 0; i < 32; ++i) { gv[i] = wg[(size_t)i * FF_]; uv[i] = wu[(size_t)i * FF_]; }
      gflag_wait(bar, 8 + l);
      if (t < 128) smem[t] = ldg_a(ws + WS_XN2 + (t >> 5) * HID_ + kcn * 32 + (t & 31));
      __syncthreads();
      float g0 = 0.f, g1 = 0.f, g2 = 0.f, g3 = 0.f;
      float u0 = 0.f, u1 = 0.f, u2 = 0.f, u3 = 0.f;
      #pragma unroll
      for (int i = 0; i < 32; ++i) {
        float g = gv[i], u = uv[i];
        float x0 = smem[i], x1 = smem[32 + i], x2 = smem[64 + i], x3 = smem[96 + i];
        g0 += g * x0; g1 += g * x1; g2 += g * x2; g3 += g * x3;
        u0 += u * x0; u1 += u * x1; u2 += u * x2; u3 += u * x3;
      }
      stg_a(ws + WS_GP + ((size_t)kcn * FF_ + col) * 4 + 0, g0);
      stg_a(ws + WS_GP + ((size_t)kcn * FF_ + col) * 4 + 1, g1);
      stg_a(ws + WS_GP + ((size_t)kcn * FF_ + col) * 4 + 2, g2);
      stg_a(ws + WS_GP + ((size_t)kcn * FF_ + col) * 4 + 3, g3);
      stg_a(ws + WS_UP + ((size_t)kcn * FF_ + col) * 4 + 0, u0);
      stg_a(ws + WS_UP + ((size_t)kcn * FF_ + col) * 4 + 1, u1);
      stg_a(ws + WS_UP + ((size_t)kcn * FF_ + col) * 4 + 2, u2);
      stg_a(ws + WS_UP + ((size_t)kcn * FF_ + col) * 4 + 3, u3);
      __syncthreads();
    }
    gbar(bar, l * 3 + 2);

    // ======== DOWN (blocks 0-175) + prefetch next-layer QKV weights (all) ========
    if (bid < 176) {
      int cb = bid & 3, kcn = bid >> 2;
      int col = cb * 256 + t;
      const float* wp = Wd + ((size_t)l * FF_ + kcn * 64) * HID_ + col;
      float wv[64];
      #pragma unroll
      for (int i = 0; i < 64; ++i) wv[i] = wp[(size_t)i * HID_];
      {
        int jj = t >> 2, bb = t & 3;
        int f = kcn * 64 + jj;
        float g = 0.f, u = 0.f;
        #pragma unroll
        for (int k2 = 0; k2 < 32; ++k2) {
          g += ldg_a(ws + WS_GP + ((size_t)k2 * FF_ + f) * 4 + bb);
          u += ldg_a(ws + WS_UP + ((size_t)k2 * FF_ + f) * 4 + bb);
        }
        float sig = 1.f / (1.f + expf(-g));
        smem[jj * 4 + bb] = g * sig * u;
      }
      __syncthreads();
      float a0 = 0.f, a1 = 0.f, a2 = 0.f, a3 = 0.f;
      #pragma unroll
      for (int i = 0; i < 64; ++i) {
        float w = wv[i];
        a0 += w * smem[i * 4 + 0]; a1 += w * smem[i * 4 + 1];
        a2 += w * smem[i * 4 + 2]; a3 += w * smem[i * 4 + 3];
      }
      stg_a(ws + WS_DP + ((size_t)kcn * 4 + 0) * 1024 + col, a0);
      stg_a(ws + WS_DP + ((size_t)kcn * 4 + 1) * 1024 + col, a1);
      stg_a(ws + WS_DP + ((size_t)kcn * 4 + 2) * 1024 + col, a2);
      stg_a(ws + WS_DP + ((size_t)kcn * 4 + 3) * 1024 + col, a3);
      __syncthreads();
      if (t == 0) sflag_add(bar, 8 + l);     // DPF: 176 producers, 4 pollers
    }
    {  // prefetch QKV weights for l+1 (read-only: safe across sync)
      int lq = (l + 1 < L_) ? l + 1 : l;
      const float* W; int stride; int wcol;
      if (qcol < 1024)      { W = Wq + (size_t)lq * HID_ * 1024; wcol = qcol;        stride = 1024; }
      else if (qcol < 1536) { W = Wk + (size_t)lq * HID_ * 512;  wcol = qcol - 1024; stride = 512;  }
      else                  { W = Wv + (size_t)lq * HID_ * 512;  wcol = qcol - 1536; stride = 512;  }
      const float* wp = W + (size_t)(qkcn * 16) * stride + wcol;
      #pragma unroll
      for (int i = 0; i < 16; ++i) wqkv[i] = wp[(size_t)i * stride];
    }

    // ======== H1 (blocks 0-3): wait DPF, residual + rms -> XN1(l+1)/out ========
    if (bid < 4) {
      sflag_wait(bar, 8 + l, 176);
      int b = bid;
      float hv[4]; float part = 0.f;
      for (int j = 0; j < 4; ++j) {
        int col = t + j * 256;
        float s = 0.f;
        #pragma unroll
        for (int k2 = 0; k2 < 44; ++k2) s += ldg_a(ws + WS_DP + ((size_t)k2 * 4 + b) * 1024 + col);
        float h = ws[WS_H2 + b * HID_ + col] + MUP_ * s;
        hv[j] = h; part += h * h;
      }
      part = wave_sum(part);
      if ((t & 63) == 0) smem[t >> 6] = part;
      __syncthreads();
      float rs = rsqrtf((smem[0] + smem[1] + smem[2] + smem[3]) * (1.0f / HID_) + EPS_);
      if (l == L_ - 1) {
        for (int j = 0; j < 4; ++j) {
          int col = t + j * 256;
          out[OUT_H + b * HID_ + col] = hv[j] * rs * fw[col];
        }
      } else {
        for (int j = 0; j < 4; ++j) {
          int col = t + j * 256;
          ws[WS_H + b * HID_ + col] = hv[j];
          stg_a(ws + WS_XN1 + b * HID_ + col, hv[j] * rs * n1[(l + 1) * HID_ + col]);
        }
        __syncthreads();
        if (t == 0) gflag_add(bar, l + 1);
      }
    }
  }
}

extern "C" void kernel_launch(void* const* d_in, const int* in_sizes, int n_in,
                              void* d_out, int out_size, void* d_ws, size_t ws_size,
                              hipStream_t stream) {
  const float* x   = (const float*)d_in[0];
  const float* kcp = (const float*)d_in[1];
  const float* vcp = (const float*)d_in[2];
  const float* Wq  = (const float*)d_in[3];
  const float* Wk  = (const float*)d_in[4];
  const float* Wv  = (const float*)d_in[5];
  const float* Wo  = (const float*)d_in[6];
  const float* Wg  = (const float*)d_in[7];
  const float* Wu  = (const float*)d_in[8];
  const float* Wd  = (const float*)d_in[9];
  const float* n1  = (const float*)d_in[10];
  const float* n2  = (const float*)d_in[11];
  const float* fw  = (const float*)d_in[12];
  const int*   pos = (const int*)d_in[13];
  float* ws  = (float*)d_ws;
  float* out = (float*)d_out;

  k_init<<<(BAR_INTS + 255) / 256, 256, 0, stream>>>(ws);

  void* args[] = { (void*)&kcp, (void*)&vcp, (void*)&Wq, (void*)&Wk, (void*)&Wv,
                   (void*)&Wo, (void*)&Wg, (void*)&Wu, (void*)&Wd, (void*)&n1,
                   (void*)&n2, (void*)&fw, (void*)&x, (void*)&pos,
                   (void*)&ws, (void*)&out };
  hipError_t e = hipLaunchCooperativeKernel((const void*)mega, dim3(512), dim3(256),
                                            args, 0, stream);
  if (e != hipSuccess) {
    mega<<<512, 256, 0, stream>>>(kcp, vcp, Wq, Wk, Wv, Wo, Wg, Wu, Wd,
                                  n1, n2, fw, x, pos, ws, out);
  }
}

// Round 8
// 604.426 us; speedup vs baseline: 5.6786x; 3.8665x over previous
//
#include <hip/hip_runtime.h>

// MiniCPM-style decode step: L=8 B=4 H=16 HKV=8 D=64 S=2048 HID=1024 FF=2816
#define L_   8
#define B_   4
#define H_   16
#define HKV_ 8
#define D_   64
#define S_   2048
#define HID_ 1024
#define FF_  2816
#define EPS_ 1e-5f
#define MUP_ 0.49497474683058327f   // 1.4/sqrt(8)
#define SCALE_ 0.125f               // 1/sqrt(64)

// d_out is FLOAT32: [h 4096 | k_upd 16384 | v_upd 16384 | pos+1]
#define OUT_H   0
#define OUT_K   4096
#define OUT_V   (4096 + 16384)
#define OUT_POS (4096 + 16384 + 16384)

// ---------------- workspace layout (floats); partials [kc][b][col] ----------------
enum {
  WS_H    = 0,                        // 4096   h at layer entry
  WS_H2   = 4096,                     // 4096   h after attn residual
  WS_QP   = 8192,                     // 32*4*2048 = 262144
  WS_AM   = WS_QP + 262144,           // 1024   [b][kv][2][16]
  WS_AL   = WS_AM + 1024,             // 1024
  WS_AO   = WS_AL + 1024,             // 64*16*64 = 65536
  WS_OP   = WS_AO + 65536,            // 16*4*1024 = 65536
  WS_GP   = WS_OP + 65536,            // 32*4*2816 = 360448
  WS_UP   = WS_GP + 360448,           // 360448
  WS_DP   = WS_UP + 360448,           // 22*4*1024 = 90112
  WS_END  = WS_DP + 90112             // ~4.9 MB
};

__device__ __forceinline__ int read_pos_dev(const int* p) {
  int v = p[0];
  if (v >= 0 && v < S_) return v;
  float f = __int_as_float(v);
  if (f >= 0.0f && f <= (float)(S_ - 1)) return (int)(f + 0.5f);
  return 1500;
}

__device__ __forceinline__ float wave_sum(float v) {
  for (int m = 1; m < 64; m <<= 1) v += __shfl_xor(v, m);
  return v;
}
__device__ __forceinline__ float wave_max(float v) {
  for (int m = 1; m < 64; m <<= 1) v = fmaxf(v, __shfl_xor(v, m));
  return v;
}

// ================= K1: QKV GEMV with fused h1 (residual+RMS) =================
// grid 256 = 8 cb x 32 kc (32 rows each), block 256
__global__ void __launch_bounds__(256)
k1_qkv(const float* __restrict__ Wq, const float* __restrict__ Wk,
       const float* __restrict__ Wv, const float* __restrict__ n1,
       const float* __restrict__ x, float* __restrict__ ws, int l) {
  int cb = blockIdx.x & 7, kc = blockIdx.x >> 3;
  int t = threadIdx.x;
  int col = cb * 256 + t;        // 0..2047: [0,1024)=q [1024,1536)=k [1536,2048)=v
  const float* W; int wcol, stride;
  if (col < 1024)      { W = Wq + (size_t)l * HID_ * 1024; wcol = col;        stride = 1024; }
  else if (col < 1536) { W = Wk + (size_t)l * HID_ * 512;  wcol = col - 1024; stride = 512;  }
  else                 { W = Wv + (size_t)l * HID_ * 512;  wcol = col - 1536; stride = 512;  }
  const float* wp = W + (size_t)(kc * 32) * stride + wcol;
  float wv[32];
  #pragma unroll
  for (int i = 0; i < 32; ++i) wv[i] = wp[(size_t)i * stride];   // weights in flight

  // fused h1: h = x (l=0) or H2 + MUP*sum(DP); full h in LDS, per-batch RMS
  __shared__ float hh[4096];
  __shared__ float red[16];
  __shared__ __align__(16) float xs[4][32];
  float part[4] = {0.f, 0.f, 0.f, 0.f};
  for (int j = 0; j < 4; ++j) {
    int c2 = t + j * 256;
    #pragma unroll
    for (int b = 0; b < 4; ++b) {
      float h;
      if (l == 0) {
        h = x[b * HID_ + c2];
      } else {
        float s = 0.f;
        #pragma unroll
        for (int k2 = 0; k2 < 22; ++k2)
          s += ws[WS_DP + ((size_t)k2 * 4 + b) * 1024 + c2];
        h = ws[WS_H2 + b * HID_ + c2] + MUP_ * s;
      }
      hh[b * HID_ + c2] = h;
      part[b] += h * h;
    }
  }
  int w = t >> 6;
  #pragma unroll
  for (int b = 0; b < 4; ++b) {
    float s = wave_sum(part[b]);
    if ((t & 63) == 0) red[w * 4 + b] = s;
  }
  __syncthreads();
  float rs[4];
  #pragma unroll
  for (int b = 0; b < 4; ++b)
    rs[b] = rsqrtf((red[b] + red[4 + b] + red[8 + b] + red[12 + b]) * (1.0f / HID_) + EPS_);
  if (blockIdx.x < 4) {          // blocks 0-3 publish H (batch = bid)
    for (int j = 0; j < 4; ++j) {
      int c2 = t + j * 256;
      ws[WS_H + blockIdx.x * HID_ + c2] = hh[blockIdx.x * HID_ + c2];
    }
  }
  if (t < 128) {
    int b = t >> 5, i = t & 31;
    int gc = kc * 32 + i;
    xs[b][i] = hh[b * HID_ + gc] * rs[b] * n1[l * HID_ + gc];
  }
  __syncthreads();
  float a0 = 0.f, a1 = 0.f, a2 = 0.f, a3 = 0.f;
  #pragma unroll
  for (int i = 0; i < 32; ++i) {
    float w_ = wv[i];
    a0 += w_ * xs[0][i]; a1 += w_ * xs[1][i];
    a2 += w_ * xs[2][i]; a3 += w_ * xs[3][i];
  }
  ws[WS_QP + ((size_t)kc * 4 + 0) * 2048 + col] = a0;
  ws[WS_QP + ((size_t)kc * 4 + 1) * 2048 + col] = a1;
  ws[WS_QP + ((size_t)kc * 4 + 2) * 2048 + col] = a2;
  ws[WS_QP + ((size_t)kc * 4 + 3) * 2048 + col] = a3;
}

// ================= K2: fused qkv-combine + rope + kv-out + flash chunk =======
// grid 512 = (b,kv) x 16 ns-chunks of 128 positions, block 256
__global__ void __launch_bounds__(256)
k2_attn(const float* __restrict__ kcache, const float* __restrict__ vcache,
        const int* __restrict__ posp, float* __restrict__ ws,
        float* __restrict__ out, int l) {
  int bh = blockIdx.x >> 4, ns = blockIdx.x & 15;
  int b = bh >> 3, kv = bh & 7;
  int t = threadIdx.x;
  int w = t >> 6, lane = t & 63, r = lane >> 4, c = lane & 15;
  int pos = read_pos_dev(posp);
  __shared__ __align__(16) float qL[2][64];
  __shared__ __align__(16) float knL[64], vnL[64];
  __shared__ float rawL[256], sc0[128], sc1[128], red[8];
  __shared__ __align__(16) float oacc[2][4][64];

  // A: combine qkv partials ([kc][b][col] -> coalesced)
  int cg;
  if (t < 128)      cg = (kv * 2 + (t >> 6)) * 64 + (t & 63);
  else if (t < 192) cg = 1024 + kv * 64 + (t & 63);
  else              cg = 1536 + kv * 64 + (t & 63);
  float s = 0.f;
  #pragma unroll
  for (int q = 0; q < 32; ++q) s += ws[WS_QP + ((size_t)q * 4 + b) * 2048 + cg];
  rawL[t] = s;
  __syncthreads();
  {
    int dd = t & 63;
    if (t < 192) {   // rope q (t<128) and k (128..191)
      int idx = dd & 31;
      float inv = expf(-(float)idx * (1.0f / 32.0f) * 9.210340371976184f); // ln 1e4
      float ang = (float)pos * inv;
      float sn, cs; __sincosf(ang, &sn, &cs);
      float partner = rawL[t ^ 32];
      float rot = (dd < 32) ? -partner : partner;
      float v = rawL[t] * cs + rot * sn;
      if (t < 128) qL[t >> 6][dd] = v;
      else {
        knL[dd] = v;
        if (ns == 0) out[OUT_K + (((size_t)l * B_ + b) * HKV_ + kv) * 64 + dd] = v;
      }
    } else {
      vnL[dd] = rawL[t];
      if (ns == 0) out[OUT_V + (((size_t)l * B_ + b) * HKV_ + kv) * 64 + dd] = rawL[t];
    }
  }
  __syncthreads();
  const float* Kb = kcache + (((size_t)l * B_ + b) * HKV_ + kv) * S_ * 64;
  const float* Vb = vcache + (((size_t)l * B_ + b) * HKV_ + kv) * S_ * 64;
  int s0 = ns * 128;
  float4 q0 = *(float4*)&qL[0][4 * c];
  float4 q1 = *(float4*)&qL[1][4 * c];
  // B: scores (float4 K rows, 16 lanes/row)
  #pragma unroll
  for (int it = 0; it < 8; ++it) {
    int sp = s0 + it * 16 + w * 4 + r;
    float d0 = 0.f, d1 = 0.f;
    bool valid = (sp <= pos);
    if (valid) {
      float4 k4 = (sp == pos) ? *(float4*)&knL[4 * c]
                              : *(const float4*)&Kb[(size_t)sp * 64 + 4 * c];
      d0 = k4.x * q0.x + k4.y * q0.y + k4.z * q0.z + k4.w * q0.w;
      d1 = k4.x * q1.x + k4.y * q1.y + k4.z * q1.z + k4.w * q1.w;
    }
    #pragma unroll
    for (int m = 1; m <= 8; m <<= 1) { d0 += __shfl_xor(d0, m); d1 += __shfl_xor(d1, m); }
    if (c == 0) {
      sc0[sp - s0] = valid ? d0 * SCALE_ : -1e30f;
      sc1[sp - s0] = valid ? d1 * SCALE_ : -1e30f;
    }
  }
  __syncthreads();
  // C: chunk softmax
  float v0 = (t < 128) ? sc0[t] : -1e30f;
  float v1 = (t < 128) ? sc1[t] : -1e30f;
  float m0 = wave_max(v0), m1 = wave_max(v1);
  if (lane == 0) { red[w] = m0; red[4 + w] = m1; }
  __syncthreads();
  m0 = fmaxf(fmaxf(red[0], red[1]), fmaxf(red[2], red[3]));
  m1 = fmaxf(fmaxf(red[4], red[5]), fmaxf(red[6], red[7]));
  float e0 = (t < 128) ? expf(v0 - m0) : 0.f;
  float e1 = (t < 128) ? expf(v1 - m1) : 0.f;
  __syncthreads();
  if (t < 128) { sc0[t] = e0; sc1[t] = e1; }
  float se0 = wave_sum(e0), se1 = wave_sum(e1);
  if (lane == 0) { red[w] = se0; red[4 + w] = se1; }
  __syncthreads();
  if (t == 0) {
    int base = ((b * HKV_ + kv) * 2) * 16 + ns;
    ws[WS_AM + base] = m0;        ws[WS_AM + base + 16] = m1;
    ws[WS_AL + base] = red[0] + red[1] + red[2] + red[3];
    ws[WS_AL + base + 16] = red[4] + red[5] + red[6] + red[7];
  }
  // D: PV
  float4 a0 = make_float4(0.f, 0.f, 0.f, 0.f);
  float4 a1 = make_float4(0.f, 0.f, 0.f, 0.f);
  #pragma unroll
  for (int it = 0; it < 8; ++it) {
    int sp = s0 + it * 16 + w * 4 + r;
    if (sp <= pos) {
      float4 v4 = (sp == pos) ? *(float4*)&vnL[4 * c]
                              : *(const float4*)&Vb[(size_t)sp * 64 + 4 * c];
      float p0 = sc0[sp - s0], p1 = sc1[sp - s0];
      a0.x += p0 * v4.x; a0.y += p0 * v4.y; a0.z += p0 * v4.z; a0.w += p0 * v4.w;
      a1.x += p1 * v4.x; a1.y += p1 * v4.y; a1.z += p1 * v4.z; a1.w += p1 * v4.w;
    }
  }
  #pragma unroll
  for (int m = 16; m <= 32; m <<= 1) {
    a0.x += __shfl_xor(a0.x, m); a0.y += __shfl_xor(a0.y, m);
    a0.z += __shfl_xor(a0.z, m); a0.w += __shfl_xor(a0.w, m);
    a1.x += __shfl_xor(a1.x, m); a1.y += __shfl_xor(a1.y, m);
    a1.z += __shfl_xor(a1.z, m); a1.w += __shfl_xor(a1.w, m);
  }
  if (r == 0) {
    *(float4*)&oacc[0][w][4 * c] = a0;
    *(float4*)&oacc[1][w][4 * c] = a1;
  }
  __syncthreads();
  if (t < 64) {
    float r0 = oacc[0][0][t] + oacc[0][1][t] + oacc[0][2][t] + oacc[0][3][t];
    float r1 = oacc[1][0][t] + oacc[1][1][t] + oacc[1][2][t] + oacc[1][3][t];
    int h0 = kv * 2;
    ws[WS_AO + ((size_t)(b * H_ + h0)     * 16 + ns) * 64 + t] = r0;
    ws[WS_AO + ((size_t)(b * H_ + h0 + 1) * 16 + ns) * 64 + t] = r1;
  }
}

// ================= K3: o-proj GEMV with fused softmax-combine ================
// grid 64 = 4 cb x 16 kc (64 rows each)
__global__ void __launch_bounds__(256)
k3_oproj(const float* __restrict__ Wo, float* __restrict__ ws, int l) {
  int cb = blockIdx.x & 3, kc = blockIdx.x >> 2;
  int t = threadIdx.x;
  int col = cb * 256 + t;
  __shared__ __align__(16) float oT[64][4];
  {
    int jj = t >> 2, bb = t & 3;
    int dim = kc * 64 + jj, h = dim >> 6, d = dim & 63;
    int mb = ((bb * HKV_ + (h >> 1)) * 2 + (h & 1)) * 16;
    float mx = -1e30f;
    #pragma unroll
    for (int n = 0; n < 16; ++n) mx = fmaxf(mx, ws[WS_AM + mb + n]);
    float ls = 0.f, os = 0.f;
    #pragma unroll
    for (int n = 0; n < 16; ++n) {
      float wg = expf(ws[WS_AM + mb + n] - mx);
      ls += wg * ws[WS_AL + mb + n];
      os += wg * ws[WS_AO + ((size_t)(bb * H_ + h) * 16 + n) * 64 + d];
    }
    oT[jj][bb] = os / ls;
  }
  __syncthreads();
  const float* wp = Wo + ((size_t)l * HID_ + kc * 64) * HID_ + col;
  float a0 = 0.f, a1 = 0.f, a2 = 0.f, a3 = 0.f;
  #pragma unroll
  for (int i = 0; i < 64; ++i) {
    float w_ = wp[(size_t)i * HID_];
    float4 o4 = *(float4*)&oT[i][0];
    a0 += w_ * o4.x; a1 += w_ * o4.y; a2 += w_ * o4.z; a3 += w_ * o4.w;
  }
  ws[WS_OP + ((size_t)kc * 4 + 0) * 1024 + col] = a0;
  ws[WS_OP + ((size_t)kc * 4 + 1) * 1024 + col] = a1;
  ws[WS_OP + ((size_t)kc * 4 + 2) * 1024 + col] = a2;
  ws[WS_OP + ((size_t)kc * 4 + 3) * 1024 + col] = a3;
}

// ================= K4: gate/up GEMV with fused h2 (residual+RMS) =============
// grid 352 = 11 cb x 32 kc (32 rows each)
__global__ void __launch_bounds__(256)
k4_gateup(const float* __restrict__ Wg, const float* __restrict__ Wu,
          const float* __restrict__ n2, float* __restrict__ ws, int l) {
  int cb = blockIdx.x % 11, kc = blockIdx.x / 11;
  int t = threadIdx.x;
  int col = cb * 256 + t;   // <2816
  const float* wgp = Wg + ((size_t)l * HID_ + kc * 32) * FF_ + col;
  const float* wup = Wu + ((size_t)l * HID_ + kc * 32) * FF_ + col;
  float gv[32], uv[32];
  #pragma unroll
  for (int i = 0; i < 32; ++i) { gv[i] = wgp[(size_t)i * FF_]; uv[i] = wup[(size_t)i * FF_]; }

  // fused h2 = H + MUP*sum(OP); RMS
  __shared__ float hh[4096];
  __shared__ float red[16];
  __shared__ __align__(16) float xs[4][32];
  float part[4] = {0.f, 0.f, 0.f, 0.f};
  for (int j = 0; j < 4; ++j) {
    int c2 = t + j * 256;
    #pragma unroll
    for (int b = 0; b < 4; ++b) {
      float s = 0.f;
      #pragma unroll
      for (int k2 = 0; k2 < 16; ++k2)
        s += ws[WS_OP + ((size_t)k2 * 4 + b) * 1024 + c2];
      float h = ws[WS_H + b * HID_ + c2] + MUP_ * s;
      hh[b * HID_ + c2] = h;
      part[b] += h * h;
    }
  }
  int w = t >> 6;
  #pragma unroll
  for (int b = 0; b < 4; ++b) {
    float s = wave_sum(part[b]);
    if ((t & 63) == 0) red[w * 4 + b] = s;
  }
  __syncthreads();
  float rs[4];
  #pragma unroll
  for (int b = 0; b < 4; ++b)
    rs[b] = rsqrtf((red[b] + red[4 + b] + red[8 + b] + red[12 + b]) * (1.0f / HID_) + EPS_);
  if (blockIdx.x < 4) {      // publish H2 (batch = bid)
    for (int j = 0; j < 4; ++j) {
      int c2 = t + j * 256;
      ws[WS_H2 + blockIdx.x * HID_ + c2] = hh[blockIdx.x * HID_ + c2];
    }
  }
  if (t < 128) {
    int b = t >> 5, i = t & 31;
    int gc = kc * 32 + i;
    xs[b][i] = hh[b * HID_ + gc] * rs[b] * n2[l * HID_ + gc];
  }
  __syncthreads();
  float g0 = 0.f, g1 = 0.f, g2 = 0.f, g3 = 0.f;
  float u0 = 0.f, u1 = 0.f, u2 = 0.f, u3 = 0.f;
  #pragma unroll
  for (int i = 0; i < 32; ++i) {
    float g = gv[i], u = uv[i];
    float x0 = xs[0][i], x1 = xs[1][i], x2 = xs[2][i], x3 = xs[3][i];
    g0 += g * x0; g1 += g * x1; g2 += g * x2; g3 += g * x3;
    u0 += u * x0; u1 += u * x1; u2 += u * x2; u3 += u * x3;
  }
  ws[WS_GP + ((size_t)kc * 4 + 0) * FF_ + col] = g0;
  ws[WS_GP + ((size_t)kc * 4 + 1) * FF_ + col] = g1;
  ws[WS_GP + ((size_t)kc * 4 + 2) * FF_ + col] = g2;
  ws[WS_GP + ((size_t)kc * 4 + 3) * FF_ + col] = g3;
  ws[WS_UP + ((size_t)kc * 4 + 0) * FF_ + col] = u0;
  ws[WS_UP + ((size_t)kc * 4 + 1) * FF_ + col] = u1;
  ws[WS_UP + ((size_t)kc * 4 + 2) * FF_ + col] = u2;
  ws[WS_UP + ((size_t)kc * 4 + 3) * FF_ + col] = u3;
}

// ================= K5: down GEMV with fused silu-combine =====================
// grid 88 = 4 cb x 22 kc (128 rows each)
__global__ void __launch_bounds__(256)
k5_down(const float* __restrict__ Wd, float* __restrict__ ws, int l) {
  int cb = blockIdx.x & 3, kc = blockIdx.x >> 2;   // kc<22
  int t = threadIdx.x;
  int col = cb * 256 + t;
  __shared__ __align__(16) float mT[128][4];
  for (int p = t; p < 512; p += 256) {
    int jj = p >> 2, bb = p & 3;
    int f = kc * 128 + jj;
    float g = 0.f, u = 0.f;
    #pragma unroll
    for (int k2 = 0; k2 < 32; ++k2) {
      g += ws[WS_GP + ((size_t)k2 * 4 + bb) * FF_ + f];
      u += ws[WS_UP + ((size_t)k2 * 4 + bb) * FF_ + f];
    }
    float sig = 1.f / (1.f + expf(-g));
    mT[jj][bb] = g * sig * u;
  }
  __syncthreads();
  const float* wp = Wd + ((size_t)l * FF_ + kc * 128) * HID_ + col;
  float a0 = 0.f, a1 = 0.f, a2 = 0.f, a3 = 0.f;
  #pragma unroll 8
  for (int i = 0; i < 128; ++i) {
    float w_ = wp[(size_t)i * HID_];
    float4 m4 = *(float4*)&mT[i][0];
    a0 += w_ * m4.x; a1 += w_ * m4.y; a2 += w_ * m4.z; a3 += w_ * m4.w;
  }
  ws[WS_DP + ((size_t)kc * 4 + 0) * 1024 + col] = a0;
  ws[WS_DP + ((size_t)kc * 4 + 1) * 1024 + col] = a1;
  ws[WS_DP + ((size_t)kc * 4 + 2) * 1024 + col] = a2;
  ws[WS_DP + ((size_t)kc * 4 + 3) * 1024 + col] = a3;
}

// ================= K6: final residual + RMS -> out, plus pos+1 ===============
__global__ void __launch_bounds__(256)
k6_final(const float* __restrict__ fw, const int* __restrict__ posp,
         float* __restrict__ ws, float* __restrict__ out) {
  int b = blockIdx.x, t = threadIdx.x;
  __shared__ float red[4];
  float hv[4];
  float part = 0.f;
  for (int j = 0; j < 4; ++j) {
    int c2 = t + j * 256;
    float s = 0.f;
    #pragma unroll
    for (int k2 = 0; k2 < 22; ++k2)
      s += ws[WS_DP + ((size_t)k2 * 4 + b) * 1024 + c2];
    float h = ws[WS_H2 + b * HID_ + c2] + MUP_ * s;
    hv[j] = h; part += h * h;
  }
  part = wave_sum(part);
  if ((t & 63) == 0) red[t >> 6] = part;
  __syncthreads();
  float rs = rsqrtf((red[0] + red[1] + red[2] + red[3]) * (1.0f / HID_) + EPS_);
  for (int j = 0; j < 4; ++j) {
    int c2 = t + j * 256;
    out[OUT_H + b * HID_ + c2] = hv[j] * rs * fw[c2];
  }
  if (b == 0 && t == 0) out[OUT_POS] = (float)(read_pos_dev(posp) + 1);
}

extern "C" void kernel_launch(void* const* d_in, const int* in_sizes, int n_in,
                              void* d_out, int out_size, void* d_ws, size_t ws_size,
                              hipStream_t stream) {
  const float* x   = (const float*)d_in[0];
  const float* kcp = (const float*)d_in[1];
  const float* vcp = (const float*)d_in[2];
  const float* Wq  = (const float*)d_in[3];
  const float* Wk  = (const float*)d_in[4];
  const float* Wv  = (const float*)d_in[5];
  const float* Wo  = (const float*)d_in[6];
  const float* Wg  = (const float*)d_in[7];
  const float* Wu  = (const float*)d_in[8];
  const float* Wd  = (const float*)d_in[9];
  const float* n1  = (const float*)d_in[10];
  const float* n2  = (const float*)d_in[11];
  const float* fw  = (const float*)d_in[12];
  const int*   pos = (const int*)d_in[13];
  float* ws  = (float*)d_ws;
  float* out = (float*)d_out;

  for (int l = 0; l < L_; ++l) {
    k1_qkv   <<<256, 256, 0, stream>>>(Wq, Wk, Wv, n1, x, ws, l);
    k2_attn  <<<512, 256, 0, stream>>>(kcp, vcp, pos, ws, out, l);
    k3_oproj <<< 64, 256, 0, stream>>>(Wo, ws, l);
    k4_gateup<<<352, 256, 0, stream>>>(Wg, Wu, n2, ws, l);
    k5_down  <<< 88, 256, 0, stream>>>(Wd, ws, l);
  }
  k6_final<<<4, 256, 0, stream>>>(fw, pos, ws, out);
}

// Round 9
// 316.948 us; speedup vs baseline: 10.8292x; 1.9070x over previous
//
#include <hip/hip_runtime.h>

// MiniCPM-style decode step: L=8 B=4 H=16 HKV=8 D=64 S=2048 HID=1024 FF=2816
#define L_   8
#define B_   4
#define H_   16
#define HKV_ 8
#define D_   64
#define S_   2048
#define HID_ 1024
#define FF_  2816
#define EPS_ 1e-5f
#define MUP_ 0.49497474683058327f   // 1.4/sqrt(8)
#define SCALE_ 0.125f               // 1/sqrt(64)
#define NCH_ 32                     // attention chunks of 64 positions

// d_out is FLOAT32: [h 4096 | k_upd 16384 | v_upd 16384 | pos+1]
#define OUT_H   0
#define OUT_K   4096
#define OUT_V   (4096 + 16384)
#define OUT_POS (4096 + 16384 + 16384)

// ---------------- workspace layout (floats); partials [kc][b][col] ----------------
enum {
  WS_HC  = 0,                        // 4096   live hidden state (atomics target)
  WS_QP  = 4096,                     // 32*4*2048 = 262144
  WS_AM  = WS_QP + 262144,           // 2048   [b][kv][2][32]
  WS_AL  = WS_AM + 2048,             // 2048
  WS_AO  = WS_AL + 2048,             // 4*16*32*64 = 131072
  WS_GP  = WS_AO + 131072,           // 32*4*2816 = 360448
  WS_UP  = WS_GP + 360448,           // 360448
  WS_END = WS_UP + 360448            // ~4.5 MB
};

__device__ __forceinline__ int read_pos_dev(const int* p) {
  int v = p[0];
  if (v >= 0 && v < S_) return v;
  float f = __int_as_float(v);
  if (f >= 0.0f && f <= (float)(S_ - 1)) return (int)(f + 0.5f);
  return 1500;
}

__device__ __forceinline__ float wave_sum(float v) {
  for (int m = 1; m < 64; m <<= 1) v += __shfl_xor(v, m);
  return v;
}
__device__ __forceinline__ float wave_max(float v) {
  for (int m = 1; m < 64; m <<= 1) v = fmaxf(v, __shfl_xor(v, m));
  return v;
}

// shared RMS prologue: read 4x1024 h, per-batch rsqrt(mean sq)
__device__ __forceinline__ void rms_of(const float* hsrc, float* red, float* rs) {
  int t = threadIdx.x;
  float part[4] = {0.f, 0.f, 0.f, 0.f};
  #pragma unroll
  for (int j = 0; j < 4; ++j) {
    int c2 = t + j * 256;
    #pragma unroll
    for (int b = 0; b < 4; ++b) {
      float v = hsrc[b * HID_ + c2];
      part[b] += v * v;
    }
  }
  int w = t >> 6;
  #pragma unroll
  for (int b = 0; b < 4; ++b) {
    float s = wave_sum(part[b]);
    if ((t & 63) == 0) red[w * 4 + b] = s;
  }
  __syncthreads();
  #pragma unroll
  for (int b = 0; b < 4; ++b)
    rs[b] = rsqrtf((red[b] + red[4 + b] + red[8 + b] + red[12 + b]) * (1.0f / HID_) + EPS_);
}

// ================= K1: QKV GEMV (RMS prologue, no combine) =================
// grid 256 = 8 cb x 32 kc (32 rows each)
__global__ void __launch_bounds__(256)
k1_qkv(const float* __restrict__ Wq, const float* __restrict__ Wk,
       const float* __restrict__ Wv, const float* __restrict__ n1,
       const float* __restrict__ x, float* __restrict__ ws, int l) {
  int cb = blockIdx.x & 7, kc = blockIdx.x >> 3;
  int t = threadIdx.x;
  int col = cb * 256 + t;
  const float* W; int wcol, stride;
  if (col < 1024)      { W = Wq + (size_t)l * HID_ * 1024; wcol = col;        stride = 1024; }
  else if (col < 1536) { W = Wk + (size_t)l * HID_ * 512;  wcol = col - 1024; stride = 512;  }
  else                 { W = Wv + (size_t)l * HID_ * 512;  wcol = col - 1536; stride = 512;  }
  const float* wp = W + (size_t)(kc * 32) * stride + wcol;
  float wv[32];
  #pragma unroll
  for (int i = 0; i < 32; ++i) wv[i] = wp[(size_t)i * stride];   // in flight

  const float* hsrc = (l == 0) ? x : (ws + WS_HC);
  __shared__ float red[16];
  __shared__ __align__(16) float xs[4][32];
  float rs[4];
  rms_of(hsrc, red, rs);
  if (l == 0 && blockIdx.x < 4) {        // seed HC = x (blocks 0-3, one batch each)
    for (int j = 0; j < 4; ++j) {
      int c2 = t + j * 256;
      ws[WS_HC + blockIdx.x * HID_ + c2] = x[blockIdx.x * HID_ + c2];
    }
  }
  if (t < 128) {
    int b = t >> 5, i = t & 31;
    int gc = kc * 32 + i;
    xs[b][i] = hsrc[b * HID_ + gc] * rs[b] * n1[l * HID_ + gc];
  }
  __syncthreads();
  float a0 = 0.f, a1 = 0.f, a2 = 0.f, a3 = 0.f;
  #pragma unroll
  for (int i = 0; i < 32; ++i) {
    float w_ = wv[i];
    a0 += w_ * xs[0][i]; a1 += w_ * xs[1][i];
    a2 += w_ * xs[2][i]; a3 += w_ * xs[3][i];
  }
  ws[WS_QP + ((size_t)kc * 4 + 0) * 2048 + col] = a0;
  ws[WS_QP + ((size_t)kc * 4 + 1) * 2048 + col] = a1;
  ws[WS_QP + ((size_t)kc * 4 + 2) * 2048 + col] = a2;
  ws[WS_QP + ((size_t)kc * 4 + 3) * 2048 + col] = a3;
}

// ================= K2: qkv-combine + rope + kv-out + flash chunk (LDS-staged) ==
// grid 1024 = (b,kv) x 32 chunks of 64 positions
__global__ void __launch_bounds__(256)
k2_attn(const float* __restrict__ kcache, const float* __restrict__ vcache,
        const int* __restrict__ posp, float* __restrict__ ws,
        float* __restrict__ out, int l) {
  int bh = blockIdx.x >> 5, ns = blockIdx.x & 31;
  int b = bh >> 3, kv = bh & 7;
  int t = threadIdx.x;
  int w = t >> 6, lane = t & 63, r = lane >> 4, c = lane & 15;
  int pos = read_pos_dev(posp);
  __shared__ __align__(16) float Kst[64 * 68];   // padded rows (68) = conflict-free
  __shared__ __align__(16) float Vst[64 * 68];
  __shared__ __align__(16) float qL[2][64];
  __shared__ __align__(16) float knL[64], vnL[64];
  __shared__ float rawL[256], sc0[64], sc1[64], red[8];
  __shared__ __align__(16) float oacc[2][4][64];

  const float* Kb = kcache + (((size_t)l * B_ + b) * HKV_ + kv) * S_ * 64;
  const float* Vb = vcache + (((size_t)l * B_ + b) * HKV_ + kv) * S_ * 64;
  int s0 = ns * 64;

  // stage K/V chunk rows (branch-free float4 streams), padded-row layout
  {
    const float4* Ksrc = (const float4*)(Kb + (size_t)s0 * 64);
    const float4* Vsrc = (const float4*)(Vb + (size_t)s0 * 64);
    #pragma unroll
    for (int i = 0; i < 4; ++i) {
      int f4 = t + i * 256;                 // 0..1023
      int row = f4 >> 4, c4 = f4 & 15;
      float4 kk = Ksrc[f4];
      float4 vv = Vsrc[f4];
      *(float4*)&Kst[row * 68 + 4 * c4] = kk;
      *(float4*)&Vst[row * 68 + 4 * c4] = vv;
    }
  }

  // combine qkv partials -> rawL; rope
  int cg;
  if (t < 128)      cg = (kv * 2 + (t >> 6)) * 64 + (t & 63);
  else if (t < 192) cg = 1024 + kv * 64 + (t & 63);
  else              cg = 1536 + kv * 64 + (t & 63);
  float s = 0.f;
  #pragma unroll
  for (int q = 0; q < 32; ++q) s += ws[WS_QP + ((size_t)q * 4 + b) * 2048 + cg];
  rawL[t] = s;
  __syncthreads();
  {
    int dd = t & 63;
    if (t < 192) {
      int idx = dd & 31;
      float inv = expf(-(float)idx * (1.0f / 32.0f) * 9.210340371976184f);
      float ang = (float)pos * inv;
      float sn, cs; __sincosf(ang, &sn, &cs);
      float partner = rawL[t ^ 32];
      float rot = (dd < 32) ? -partner : partner;
      float v = rawL[t] * cs + rot * sn;
      if (t < 128) qL[t >> 6][dd] = v;
      else {
        knL[dd] = v;
        if (ns == 0) out[OUT_K + (((size_t)l * B_ + b) * HKV_ + kv) * 64 + dd] = v;
      }
    } else {
      vnL[dd] = rawL[t];
      if (ns == 0) out[OUT_V + (((size_t)l * B_ + b) * HKV_ + kv) * 64 + dd] = rawL[t];
    }
  }
  __syncthreads();
  // substitute the new-token row if it falls in this chunk
  if (pos >= s0 && pos < s0 + 64) {
    int row = pos - s0;
    if (t < 64)                Kst[row * 68 + t] = knL[t];
    else if (t < 128)          Vst[row * 68 + (t - 64)] = vnL[t - 64];
  }
  __syncthreads();

  float4 q0 = *(float4*)&qL[0][4 * c];
  float4 q1 = *(float4*)&qL[1][4 * c];
  // scores from LDS
  #pragma unroll
  for (int it = 0; it < 4; ++it) {
    int row = it * 16 + w * 4 + r;
    int sp = s0 + row;
    float4 k4 = *(float4*)&Kst[row * 68 + 4 * c];
    float d0 = k4.x * q0.x + k4.y * q0.y + k4.z * q0.z + k4.w * q0.w;
    float d1 = k4.x * q1.x + k4.y * q1.y + k4.z * q1.z + k4.w * q1.w;
    #pragma unroll
    for (int m = 1; m <= 8; m <<= 1) { d0 += __shfl_xor(d0, m); d1 += __shfl_xor(d1, m); }
    if (c == 0) {
      bool valid = (sp <= pos);
      sc0[row] = valid ? d0 * SCALE_ : -1e30f;
      sc1[row] = valid ? d1 * SCALE_ : -1e30f;
    }
  }
  __syncthreads();
  // chunk softmax
  float v0 = (t < 64) ? sc0[t] : -1e30f;
  float v1 = (t < 64) ? sc1[t] : -1e30f;
  float m0 = wave_max(v0), m1 = wave_max(v1);
  if (lane == 0) { red[w] = m0; red[4 + w] = m1; }
  __syncthreads();
  m0 = fmaxf(fmaxf(red[0], red[1]), fmaxf(red[2], red[3]));
  m1 = fmaxf(fmaxf(red[4], red[5]), fmaxf(red[6], red[7]));
  float e0 = (t < 64) ? expf(v0 - m0) : 0.f;
  float e1 = (t < 64) ? expf(v1 - m1) : 0.f;
  __syncthreads();
  if (t < 64) { sc0[t] = e0; sc1[t] = e1; }
  float se0 = wave_sum(e0), se1 = wave_sum(e1);
  if (lane == 0) { red[w] = se0; red[4 + w] = se1; }
  __syncthreads();
  if (t == 0) {
    int base = ((b * HKV_ + kv) * 2) * NCH_ + ns;
    ws[WS_AM + base] = m0;          ws[WS_AM + base + NCH_] = m1;
    ws[WS_AL + base] = red[0] + red[1] + red[2] + red[3];
    ws[WS_AL + base + NCH_] = red[4] + red[5] + red[6] + red[7];
  }
  // PV from LDS
  float4 a0 = make_float4(0.f, 0.f, 0.f, 0.f);
  float4 a1 = make_float4(0.f, 0.f, 0.f, 0.f);
  #pragma unroll
  for (int it = 0; it < 4; ++it) {
    int row = it * 16 + w * 4 + r;
    float4 v4 = *(float4*)&Vst[row * 68 + 4 * c];
    float p0 = sc0[row], p1 = sc1[row];
    a0.x += p0 * v4.x; a0.y += p0 * v4.y; a0.z += p0 * v4.z; a0.w += p0 * v4.w;
    a1.x += p1 * v4.x; a1.y += p1 * v4.y; a1.z += p1 * v4.z; a1.w += p1 * v4.w;
  }
  #pragma unroll
  for (int m = 16; m <= 32; m <<= 1) {
    a0.x += __shfl_xor(a0.x, m); a0.y += __shfl_xor(a0.y, m);
    a0.z += __shfl_xor(a0.z, m); a0.w += __shfl_xor(a0.w, m);
    a1.x += __shfl_xor(a1.x, m); a1.y += __shfl_xor(a1.y, m);
    a1.z += __shfl_xor(a1.z, m); a1.w += __shfl_xor(a1.w, m);
  }
  if (r == 0) {
    *(float4*)&oacc[0][w][4 * c] = a0;
    *(float4*)&oacc[1][w][4 * c] = a1;
  }
  __syncthreads();
  if (t < 64) {
    float r0 = oacc[0][0][t] + oacc[0][1][t] + oacc[0][2][t] + oacc[0][3][t];
    float r1 = oacc[1][0][t] + oacc[1][1][t] + oacc[1][2][t] + oacc[1][3][t];
    int h0 = kv * 2;
    ws[WS_AO + ((size_t)(b * H_ + h0)     * NCH_ + ns) * 64 + t] = r0;
    ws[WS_AO + ((size_t)(b * H_ + h0 + 1) * NCH_ + ns) * 64 + t] = r1;
  }
}

// ================= K3: o-proj GEMV, atomicAdd residual into HC ===============
// grid 128 = 4 cb x 32 kc (32 rows each)
__global__ void __launch_bounds__(256)
k3_oproj(const float* __restrict__ Wo, float* __restrict__ ws, int l) {
  int cb = blockIdx.x & 3, kc = blockIdx.x >> 2;
  int t = threadIdx.x;
  int col = cb * 256 + t;
  const float* wp = Wo + ((size_t)l * HID_ + kc * 32) * HID_ + col;
  float wv[32];
  #pragma unroll
  for (int i = 0; i < 32; ++i) wv[i] = wp[(size_t)i * HID_];    // in flight

  __shared__ __align__(16) float oT[32][4];
  if (t < 128) {
    int bb = t >> 5, jj = t & 31;
    int dim = kc * 32 + jj, h = dim >> 6, d = dim & 63;
    int mb = ((bb * HKV_ + (h >> 1)) * 2 + (h & 1)) * NCH_;
    float mx = -1e30f;
    #pragma unroll
    for (int n = 0; n < NCH_; ++n) mx = fmaxf(mx, ws[WS_AM + mb + n]);
    float ls = 0.f, os = 0.f;
    #pragma unroll
    for (int n = 0; n < NCH_; ++n) {
      float wg = expf(ws[WS_AM + mb + n] - mx);
      ls += wg * ws[WS_AL + mb + n];
      os += wg * ws[WS_AO + ((size_t)(bb * H_ + h) * NCH_ + n) * 64 + d];
    }
    oT[jj][bb] = os / ls;
  }
  __syncthreads();
  float a0 = 0.f, a1 = 0.f, a2 = 0.f, a3 = 0.f;
  #pragma unroll
  for (int i = 0; i < 32; ++i) {
    float w_ = wv[i];
    float4 o4 = *(float4*)&oT[i][0];
    a0 += w_ * o4.x; a1 += w_ * o4.y; a2 += w_ * o4.z; a3 += w_ * o4.w;
  }
  atomicAdd(ws + WS_HC + 0 * HID_ + col, MUP_ * a0);
  atomicAdd(ws + WS_HC + 1 * HID_ + col, MUP_ * a1);
  atomicAdd(ws + WS_HC + 2 * HID_ + col, MUP_ * a2);
  atomicAdd(ws + WS_HC + 3 * HID_ + col, MUP_ * a3);
}

// ================= K4: gate/up GEMV (RMS prologue on HC=h2) ==================
// grid 352 = 11 cb x 32 kc (32 rows each)
__global__ void __launch_bounds__(256)
k4_gateup(const float* __restrict__ Wg, const float* __restrict__ Wu,
          const float* __restrict__ n2, float* __restrict__ ws, int l) {
  int cb = blockIdx.x % 11, kc = blockIdx.x / 11;
  int t = threadIdx.x;
  int col = cb * 256 + t;
  const float* wgp = Wg + ((size_t)l * HID_ + kc * 32) * FF_ + col;
  const float* wup = Wu + ((size_t)l * HID_ + kc * 32) * FF_ + col;
  float gv[32], uv[32];
  #pragma unroll
  for (int i = 0; i < 32; ++i) { gv[i] = wgp[(size_t)i * FF_]; uv[i] = wup[(size_t)i * FF_]; }

  const float* hsrc = ws + WS_HC;
  __shared__ float red[16];
  __shared__ __align__(16) float xs[4][32];
  float rs[4];
  rms_of(hsrc, red, rs);
  if (t < 128) {
    int b = t >> 5, i = t & 31;
    int gc = kc * 32 + i;
    xs[b][i] = hsrc[b * HID_ + gc] * rs[b] * n2[l * HID_ + gc];
  }
  __syncthreads();
  float g0 = 0.f, g1 = 0.f, g2 = 0.f, g3 = 0.f;
  float u0 = 0.f, u1 = 0.f, u2 = 0.f, u3 = 0.f;
  #pragma unroll
  for (int i = 0; i < 32; ++i) {
    float g = gv[i], u = uv[i];
    float x0 = xs[0][i], x1 = xs[1][i], x2 = xs[2][i], x3 = xs[3][i];
    g0 += g * x0; g1 += g * x1; g2 += g * x2; g3 += g * x3;
    u0 += u * x0; u1 += u * x1; u2 += u * x2; u3 += u * x3;
  }
  ws[WS_GP + ((size_t)kc * 4 + 0) * FF_ + col] = g0;
  ws[WS_GP + ((size_t)kc * 4 + 1) * FF_ + col] = g1;
  ws[WS_GP + ((size_t)kc * 4 + 2) * FF_ + col] = g2;
  ws[WS_GP + ((size_t)kc * 4 + 3) * FF_ + col] = g3;
  ws[WS_UP + ((size_t)kc * 4 + 0) * FF_ + col] = u0;
  ws[WS_UP + ((size_t)kc * 4 + 1) * FF_ + col] = u1;
  ws[WS_UP + ((size_t)kc * 4 + 2) * FF_ + col] = u2;
  ws[WS_UP + ((size_t)kc * 4 + 3) * FF_ + col] = u3;
}

// ================= K5: down GEMV (silu-combine), atomicAdd into HC ===========
// grid 176 = 4 cb x 44 kc (64 rows each)
__global__ void __launch_bounds__(256)
k5_down(const float* __restrict__ Wd, float* __restrict__ ws, int l) {
  int cb = blockIdx.x & 3, kc = blockIdx.x >> 2;   // kc<44
  int t = threadIdx.x;
  int col = cb * 256 + t;
  const float* wp = Wd + ((size_t)l * FF_ + kc * 64) * HID_ + col;
  float wv[64];
  #pragma unroll
  for (int i = 0; i < 64; ++i) wv[i] = wp[(size_t)i * HID_];    // in flight

  __shared__ __align__(16) float mT[64][4];
  {
    int bb = t >> 6, jj = t & 63;       // 256 items = 64 rows x 4 batches
    int f = kc * 64 + jj;
    float g = 0.f, u = 0.f;
    #pragma unroll
    for (int k2 = 0; k2 < 32; ++k2) {
      g += ws[WS_GP + ((size_t)k2 * 4 + bb) * FF_ + f];
      u += ws[WS_UP + ((size_t)k2 * 4 + bb) * FF_ + f];
    }
    float sig = 1.f / (1.f + expf(-g));
    mT[jj][bb] = g * sig * u;
  }
  __syncthreads();
  float a0 = 0.f, a1 = 0.f, a2 = 0.f, a3 = 0.f;
  #pragma unroll
  for (int i = 0; i < 64; ++i) {
    float w_ = wv[i];
    float4 m4 = *(float4*)&mT[i][0];
    a0 += w_ * m4.x; a1 += w_ * m4.y; a2 += w_ * m4.z; a3 += w_ * m4.w;
  }
  atomicAdd(ws + WS_HC + 0 * HID_ + col, MUP_ * a0);
  atomicAdd(ws + WS_HC + 1 * HID_ + col, MUP_ * a1);
  atomicAdd(ws + WS_HC + 2 * HID_ + col, MUP_ * a2);
  atomicAdd(ws + WS_HC + 3 * HID_ + col, MUP_ * a3);
}

// ================= K6: final RMS(HC)*fw -> out, plus pos+1 ===================
__global__ void __launch_bounds__(256)
k6_final(const float* __restrict__ fw, const int* __restrict__ posp,
         float* __restrict__ ws, float* __restrict__ out) {
  int b = blockIdx.x, t = threadIdx.x;
  __shared__ float red[4];
  float hv[4];
  float part = 0.f;
  for (int j = 0; j < 4; ++j) {
    float v = ws[WS_HC + b * HID_ + t + j * 256];
    hv[j] = v; part += v * v;
  }
  part = wave_sum(part);
  if ((t & 63) == 0) red[t >> 6] = part;
  __syncthreads();
  float rs = rsqrtf((red[0] + red[1] + red[2] + red[3]) * (1.0f / HID_) + EPS_);
  for (int j = 0; j < 4; ++j) {
    int c2 = t + j * 256;
    out[OUT_H + b * HID_ + c2] = hv[j] * rs * fw[c2];
  }
  if (b == 0 && t == 0) out[OUT_POS] = (float)(read_pos_dev(posp) + 1);
}

extern "C" void kernel_launch(void* const* d_in, const int* in_sizes, int n_in,
                              void* d_out, int out_size, void* d_ws, size_t ws_size,
                              hipStream_t stream) {
  const float* x   = (const float*)d_in[0];
  const float* kcp = (const float*)d_in[1];
  const float* vcp = (const float*)d_in[2];
  const float* Wq  = (const float*)d_in[3];
  const float* Wk  = (const float*)d_in[4];
  const float* Wv  = (const float*)d_in[5];
  const float* Wo  = (const float*)d_in[6];
  const float* Wg  = (const float*)d_in[7];
  const float* Wu  = (const float*)d_in[8];
  const float* Wd  = (const float*)d_in[9];
  const float* n1  = (const float*)d_in[10];
  const float* n2  = (const float*)d_in[11];
  const float* fw  = (const float*)d_in[12];
  const int*   pos = (const int*)d_in[13];
  float* ws  = (float*)d_ws;
  float* out = (float*)d_out;

  for (int l = 0; l < L_; ++l) {
    k1_qkv   <<< 256, 256, 0, stream>>>(Wq, Wk, Wv, n1, x, ws, l);
    k2_attn  <<<1024, 256, 0, stream>>>(kcp, vcp, pos, ws, out, l);
    k3_oproj <<< 128, 256, 0, stream>>>(Wo, ws, l);
    k4_gateup<<< 352, 256, 0, stream>>>(Wg, Wu, n2, ws, l);
    k5_down  <<< 176, 256, 0, stream>>>(Wd, ws, l);
  }
  k6_final<<<4, 256, 0, stream>>>(fw, pos, ws, out);
}